// Round 1
// baseline (4608.849 us; speedup 1.0000x reference)
//
#include <hip/hip_runtime.h>

#define NN 50000
#define EE 800000
#define GG 512
#define LL 3

__device__ __forceinline__ float silu_f(float x) {
    // x * sigmoid(x); v_rcp_f32 is ~1 ulp, v_exp-based __expf ~1 ulp: plenty for fp32 tolerance
    return x * __builtin_amdgcn_rcpf(1.0f + __expf(-x));
}

// ---------------------------------------------------------------------------
// Edge-message kernel: for a tile of 128 edges,
//   cat = [h[dst], h[src]]  (E,128)
//   m   = silu(cat @ W1 + b1); m = silu(m @ W2 + b2)
//   agg[dst] += m            (atomic scatter)
// 512 threads, 4x4 register micro-tile each (rows = tr+32*jj, cols = 4*tc+ii).
// LDS ~153KB -> 1 block/CU. Inner loop is VALU-bound (64 fmaf per 8 ds_read_b128).
// ---------------------------------------------------------------------------
__global__ __launch_bounds__(512, 1) void edge_kernel(
    const float* __restrict__ h, const int* __restrict__ ei,
    const float* __restrict__ w1g, const float* __restrict__ b1g,
    const float* __restrict__ w2g, const float* __restrict__ b2g,
    float* __restrict__ agg, int ntiles)
{
    extern __shared__ float lds[];
    float* ws1  = lds;               // 128*64 = 8192
    float* ws2  = ws1 + 8192;        // 64*64  = 4096
    float* wb1  = ws2 + 4096;        // 64
    float* wb2  = wb1 + 64;          // 64
    float* cats = wb2 + 64;          // 128 rows * stride 132
    float* m1s  = cats + 128 * 132;  // 128 rows * stride 68
    int*   dsts = (int*)(m1s + 128 * 68);  // 128
    int*   srcs = dsts + 128;              // 128

    const int tid = threadIdx.x;
    const int tr  = tid & 31;        // 0..31
    const int tc  = tid >> 5;        // 0..15

    for (int i = tid; i < 2048; i += 512)
        *(float4*)&ws1[4 * i] = *(const float4*)&w1g[4 * i];
    for (int i = tid; i < 1024; i += 512)
        *(float4*)&ws2[4 * i] = *(const float4*)&w2g[4 * i];
    if (tid < 64) { wb1[tid] = b1g[tid]; wb2[tid] = b2g[tid]; }

    for (int tile = blockIdx.x; tile < ntiles; tile += gridDim.x) {
        const int ebase = tile * 128;
        __syncthreads();  // B0: prior iter's LDS reads (m1s, dsts) complete
        if (tid < 128)        dsts[tid]       = ei[EE + ebase + tid];  // edge_index[1] = dst
        else if (tid < 256)   srcs[tid - 128] = ei[ebase + tid - 128]; // edge_index[0] = src
        __syncthreads();  // B1: indices visible
        // gather cat rows: 128 edges x 32 float4 = 4096 float4, 8 per thread
#pragma unroll
        for (int rep = 0; rep < 8; ++rep) {
            int idx = rep * 512 + tid;
            int e = idx >> 5, q = idx & 31;
            const float* p = (q < 16) ? (h + 64 * dsts[e] + 4 * q)
                                      : (h + 64 * srcs[e] + 4 * (q - 16));
            *(float4*)&cats[e * 132 + 4 * q] = *(const float4*)p;
        }
        __syncthreads();  // B2
        // ---- stage 1: (128e x 128k) @ (128k x 64) ----
        float acc[4][4];
#pragma unroll
        for (int jj = 0; jj < 4; ++jj)
#pragma unroll
            for (int ii = 0; ii < 4; ++ii) acc[jj][ii] = wb1[4 * tc + ii];
#pragma unroll 4
        for (int k16 = 0; k16 < 32; ++k16) {
            float4 bv0 = *(const float4*)&ws1[(4 * k16 + 0) * 64 + 4 * tc];
            float4 bv1 = *(const float4*)&ws1[(4 * k16 + 1) * 64 + 4 * tc];
            float4 bv2 = *(const float4*)&ws1[(4 * k16 + 2) * 64 + 4 * tc];
            float4 bv3 = *(const float4*)&ws1[(4 * k16 + 3) * 64 + 4 * tc];
#pragma unroll
            for (int jj = 0; jj < 4; ++jj) {
                float4 av = *(const float4*)&cats[(tr + 32 * jj) * 132 + 4 * k16];
                acc[jj][0] = fmaf(av.x, bv0.x, fmaf(av.y, bv1.x, fmaf(av.z, bv2.x, fmaf(av.w, bv3.x, acc[jj][0]))));
                acc[jj][1] = fmaf(av.x, bv0.y, fmaf(av.y, bv1.y, fmaf(av.z, bv2.y, fmaf(av.w, bv3.y, acc[jj][1]))));
                acc[jj][2] = fmaf(av.x, bv0.z, fmaf(av.y, bv1.z, fmaf(av.z, bv2.z, fmaf(av.w, bv3.z, acc[jj][2]))));
                acc[jj][3] = fmaf(av.x, bv0.w, fmaf(av.y, bv1.w, fmaf(av.z, bv2.w, fmaf(av.w, bv3.w, acc[jj][3]))));
            }
        }
#pragma unroll
        for (int jj = 0; jj < 4; ++jj) {
            float4 v;
            v.x = silu_f(acc[jj][0]); v.y = silu_f(acc[jj][1]);
            v.z = silu_f(acc[jj][2]); v.w = silu_f(acc[jj][3]);
            *(float4*)&m1s[(tr + 32 * jj) * 68 + 4 * tc] = v;
        }
        __syncthreads();  // B3
        // ---- stage 2: (128e x 64k) @ (64k x 64) ----
        float acc2[4][4];
#pragma unroll
        for (int jj = 0; jj < 4; ++jj)
#pragma unroll
            for (int ii = 0; ii < 4; ++ii) acc2[jj][ii] = wb2[4 * tc + ii];
#pragma unroll 4
        for (int k16 = 0; k16 < 16; ++k16) {
            float4 bv0 = *(const float4*)&ws2[(4 * k16 + 0) * 64 + 4 * tc];
            float4 bv1 = *(const float4*)&ws2[(4 * k16 + 1) * 64 + 4 * tc];
            float4 bv2 = *(const float4*)&ws2[(4 * k16 + 2) * 64 + 4 * tc];
            float4 bv3 = *(const float4*)&ws2[(4 * k16 + 3) * 64 + 4 * tc];
#pragma unroll
            for (int jj = 0; jj < 4; ++jj) {
                float4 av = *(const float4*)&m1s[(tr + 32 * jj) * 68 + 4 * k16];
                acc2[jj][0] = fmaf(av.x, bv0.x, fmaf(av.y, bv1.x, fmaf(av.z, bv2.x, fmaf(av.w, bv3.x, acc2[jj][0]))));
                acc2[jj][1] = fmaf(av.x, bv0.y, fmaf(av.y, bv1.y, fmaf(av.z, bv2.y, fmaf(av.w, bv3.y, acc2[jj][1]))));
                acc2[jj][2] = fmaf(av.x, bv0.z, fmaf(av.y, bv1.z, fmaf(av.z, bv2.z, fmaf(av.w, bv3.z, acc2[jj][2]))));
                acc2[jj][3] = fmaf(av.x, bv0.w, fmaf(av.y, bv1.w, fmaf(av.z, bv2.w, fmaf(av.w, bv3.w, acc2[jj][3]))));
            }
        }
#pragma unroll
        for (int jj = 0; jj < 4; ++jj) {
            int d = dsts[tr + 32 * jj];
            float* bp = agg + 64 * d + 4 * tc;
            atomicAdd(bp + 0, silu_f(acc2[jj][0]));
            atomicAdd(bp + 1, silu_f(acc2[jj][1]));
            atomicAdd(bp + 2, silu_f(acc2[jj][2]));
            atomicAdd(bp + 3, silu_f(acc2[jj][3]));
        }
    }
}

// ---------------------------------------------------------------------------
// Row-MLP kernel: tiles of 128 rows.
//   K1==128: in = [A_row | A2_row]   (node update: h | agg)
//   K1==64 : in = A_row              (readout stage)
//   t = silu(in @ W1 + b1); o = t @ W2 + b2 (optional silu)
//   RESID: o += A_row (first 64 cols of staged input); write o to outp[n]
//   SCATTER: atomicAdd into outp[seg[n]*64 + col]
// ---------------------------------------------------------------------------
template <int K1, bool SILU2, bool RESID, bool SCATTER>
__global__ __launch_bounds__(512, 1) void rowmlp_kernel(
    const float* __restrict__ A, const float* __restrict__ A2,
    const float* __restrict__ w1g, const float* __restrict__ b1g,
    const float* __restrict__ w2g, const float* __restrict__ b2g,
    const int* __restrict__ seg, float* __restrict__ outp,
    int nrows, int ntiles)
{
    constexpr int CST = K1 + 4;            // padded LDS row stride (floats)
    constexpr int QN  = K1 / 4;            // float4s per staged row
    constexpr int QSH = (K1 == 128) ? 5 : 4;
    constexpr int REPS = QN / 4;           // gather reps (8 or 4)

    extern __shared__ float lds[];
    float* ws1  = lds;                     // K1*64
    float* ws2  = ws1 + K1 * 64;           // 4096
    float* wb1  = ws2 + 4096;
    float* wb2  = wb1 + 64;
    float* cats = wb2 + 64;                // 128*CST
    float* m1s  = cats + 128 * CST;        // 128*68
    int*   segs = (int*)(m1s + 128 * 68);  // 128

    const int tid = threadIdx.x;
    const int tr  = tid & 31;
    const int tc  = tid >> 5;

    for (int i = tid; i < K1 * 16; i += 512)
        *(float4*)&ws1[4 * i] = *(const float4*)&w1g[4 * i];
    for (int i = tid; i < 1024; i += 512)
        *(float4*)&ws2[4 * i] = *(const float4*)&w2g[4 * i];
    if (tid < 64) { wb1[tid] = b1g[tid]; wb2[tid] = b2g[tid]; }

    for (int tile = blockIdx.x; tile < ntiles; tile += gridDim.x) {
        const int base = tile * 128;
        __syncthreads();  // B0
        if (SCATTER) {
            if (tid < 128) segs[tid] = (base + tid < nrows) ? seg[base + tid] : 0;
        }
        // gather rows (coalesced); zero-fill the tail
#pragma unroll
        for (int rep = 0; rep < REPS; ++rep) {
            int idx = rep * 512 + tid;
            int r = idx >> QSH, q = idx & (QN - 1);
            int n = base + r;
            float4 v = make_float4(0.f, 0.f, 0.f, 0.f);
            if (n < nrows) {
                if constexpr (K1 == 128)
                    v = (q < 16) ? *(const float4*)(A + 64 * n + 4 * q)
                                 : *(const float4*)(A2 + 64 * n + 4 * (q - 16));
                else
                    v = *(const float4*)(A + 64 * n + 4 * q);
            }
            *(float4*)&cats[r * CST + 4 * q] = v;
        }
        __syncthreads();  // B2 (also makes segs visible)
        float acc[4][4];
#pragma unroll
        for (int jj = 0; jj < 4; ++jj)
#pragma unroll
            for (int ii = 0; ii < 4; ++ii) acc[jj][ii] = wb1[4 * tc + ii];
#pragma unroll 4
        for (int k16 = 0; k16 < K1 / 4; ++k16) {
            float4 bv0 = *(const float4*)&ws1[(4 * k16 + 0) * 64 + 4 * tc];
            float4 bv1 = *(const float4*)&ws1[(4 * k16 + 1) * 64 + 4 * tc];
            float4 bv2 = *(const float4*)&ws1[(4 * k16 + 2) * 64 + 4 * tc];
            float4 bv3 = *(const float4*)&ws1[(4 * k16 + 3) * 64 + 4 * tc];
#pragma unroll
            for (int jj = 0; jj < 4; ++jj) {
                float4 av = *(const float4*)&cats[(tr + 32 * jj) * CST + 4 * k16];
                acc[jj][0] = fmaf(av.x, bv0.x, fmaf(av.y, bv1.x, fmaf(av.z, bv2.x, fmaf(av.w, bv3.x, acc[jj][0]))));
                acc[jj][1] = fmaf(av.x, bv0.y, fmaf(av.y, bv1.y, fmaf(av.z, bv2.y, fmaf(av.w, bv3.y, acc[jj][1]))));
                acc[jj][2] = fmaf(av.x, bv0.z, fmaf(av.y, bv1.z, fmaf(av.z, bv2.z, fmaf(av.w, bv3.z, acc[jj][2]))));
                acc[jj][3] = fmaf(av.x, bv0.w, fmaf(av.y, bv1.w, fmaf(av.z, bv2.w, fmaf(av.w, bv3.w, acc[jj][3]))));
            }
        }
#pragma unroll
        for (int jj = 0; jj < 4; ++jj) {
            float4 v;
            v.x = silu_f(acc[jj][0]); v.y = silu_f(acc[jj][1]);
            v.z = silu_f(acc[jj][2]); v.w = silu_f(acc[jj][3]);
            *(float4*)&m1s[(tr + 32 * jj) * 68 + 4 * tc] = v;
        }
        __syncthreads();  // B3
        float acc2[4][4];
#pragma unroll
        for (int jj = 0; jj < 4; ++jj)
#pragma unroll
            for (int ii = 0; ii < 4; ++ii) acc2[jj][ii] = wb2[4 * tc + ii];
#pragma unroll 4
        for (int k16 = 0; k16 < 16; ++k16) {
            float4 bv0 = *(const float4*)&ws2[(4 * k16 + 0) * 64 + 4 * tc];
            float4 bv1 = *(const float4*)&ws2[(4 * k16 + 1) * 64 + 4 * tc];
            float4 bv2 = *(const float4*)&ws2[(4 * k16 + 2) * 64 + 4 * tc];
            float4 bv3 = *(const float4*)&ws2[(4 * k16 + 3) * 64 + 4 * tc];
#pragma unroll
            for (int jj = 0; jj < 4; ++jj) {
                float4 av = *(const float4*)&m1s[(tr + 32 * jj) * 68 + 4 * k16];
                acc2[jj][0] = fmaf(av.x, bv0.x, fmaf(av.y, bv1.x, fmaf(av.z, bv2.x, fmaf(av.w, bv3.x, acc2[jj][0]))));
                acc2[jj][1] = fmaf(av.x, bv0.y, fmaf(av.y, bv1.y, fmaf(av.z, bv2.y, fmaf(av.w, bv3.y, acc2[jj][1]))));
                acc2[jj][2] = fmaf(av.x, bv0.z, fmaf(av.y, bv1.z, fmaf(av.z, bv2.z, fmaf(av.w, bv3.z, acc2[jj][2]))));
                acc2[jj][3] = fmaf(av.x, bv0.w, fmaf(av.y, bv1.w, fmaf(av.z, bv2.w, fmaf(av.w, bv3.w, acc2[jj][3]))));
            }
        }
#pragma unroll
        for (int jj = 0; jj < 4; ++jj) {
            int r = tr + 32 * jj;
            int n = base + r;
            float v[4];
#pragma unroll
            for (int ii = 0; ii < 4; ++ii)
                v[ii] = SILU2 ? silu_f(acc2[jj][ii]) : acc2[jj][ii];
            if (RESID) {
                float4 hold = *(const float4*)&cats[r * CST + 4 * tc];
                v[0] += hold.x; v[1] += hold.y; v[2] += hold.z; v[3] += hold.w;
            }
            if (n < nrows) {
                if (SCATTER) {
                    float* bp = outp + 64 * segs[r] + 4 * tc;
                    atomicAdd(bp + 0, v[0]); atomicAdd(bp + 1, v[1]);
                    atomicAdd(bp + 2, v[2]); atomicAdd(bp + 3, v[3]);
                } else {
                    *(float4*)&outp[64 * n + 4 * tc] = make_float4(v[0], v[1], v[2], v[3]);
                }
            }
        }
    }
}

// h = x @ proj_w + proj_b   (N x 14) @ (14 x 64)
__global__ __launch_bounds__(256) void proj_kernel(
    const float* __restrict__ x, const float* __restrict__ w,
    const float* __restrict__ b, float* __restrict__ h, int n)
{
    int i = blockIdx.x * 256 + threadIdx.x;  // i = node*64 + j
    if (i >= n * 64) return;
    int node = i >> 6, j = i & 63;
    const float* xr = x + node * 14;
    float acc = b[j];
#pragma unroll
    for (int k = 0; k < 14; ++k) acc = fmaf(xr[k], w[k * 64 + j], acc);
    h[i] = acc;
}

// out[g] = silu(gsum[g] @ lin3 + b3) @ lin4 + b4 ; one wave per graph
__global__ __launch_bounds__(256) void head_kernel(
    const float* __restrict__ gsum,
    const float* __restrict__ w3, const float* __restrict__ b3,
    const float* __restrict__ w4, const float* __restrict__ b4,
    float* __restrict__ out, int g_count)
{
    int wid  = (blockIdx.x * 256 + threadIdx.x) >> 6;
    int lane = threadIdx.x & 63;
    if (wid >= g_count) return;
    float v = gsum[wid * 64 + lane];
    float t = b3[lane];
#pragma unroll
    for (int k = 0; k < 64; ++k) {
        float a = __shfl(v, k, 64);
        t = fmaf(a, w3[k * 64 + lane], t);
    }
    t = silu_f(t);
    float r = t * w4[lane];
#pragma unroll
    for (int off = 32; off; off >>= 1) r += __shfl_down(r, off, 64);
    if (lane == 0) out[wid] = r + b4[0];
}

extern "C" void kernel_launch(void* const* d_in, const int* in_sizes, int n_in,
                              void* d_out, int out_size, void* d_ws, size_t ws_size,
                              hipStream_t stream)
{
    const float* x      = (const float*)d_in[0];
    // d_in[1] = pos : unused by the reference
    const int*   ei     = (const int*)d_in[2];
    const int*   batch  = (const int*)d_in[3];
    const float* proj_w = (const float*)d_in[4];
    const float* proj_b = (const float*)d_in[5];
    const float* ew1 = (const float*)d_in[6];
    const float* eb1 = (const float*)d_in[7];
    const float* ew2 = (const float*)d_in[8];
    const float* eb2 = (const float*)d_in[9];
    const float* nw1 = (const float*)d_in[10];
    const float* nb1 = (const float*)d_in[11];
    const float* nw2 = (const float*)d_in[12];
    const float* nb2 = (const float*)d_in[13];
    const float* l1w = (const float*)d_in[14]; const float* l1b = (const float*)d_in[15];
    const float* l2w = (const float*)d_in[16]; const float* l2b = (const float*)d_in[17];
    const float* l3w = (const float*)d_in[18]; const float* l3b = (const float*)d_in[19];
    const float* l4w = (const float*)d_in[20]; const float* l4b = (const float*)d_in[21];

    float* out  = (float*)d_out;
    float* h    = out + GG;            // per_atom_out region doubles as h [N,64]
    float* agg  = (float*)d_ws;        // [N,64]
    float* gsum = agg + (size_t)NN * 64;  // [G,64]

    const size_t edge_lds = (size_t)(8192 + 4096 + 128 + 128 * 132 + 128 * 68) * 4 + 256 * 4;
    const size_t node_lds = (size_t)(8192 + 4096 + 128 + 128 * 132 + 128 * 68) * 4 + 128 * 4;
    const size_t ro_lds   = (size_t)(4096 + 4096 + 128 + 128 * 68 + 128 * 68) * 4 + 128 * 4;

    (void)hipFuncSetAttribute((const void*)edge_kernel,
                              hipFuncAttributeMaxDynamicSharedMemorySize, (int)edge_lds);
    (void)hipFuncSetAttribute((const void*)(rowmlp_kernel<128, false, true, false>),
                              hipFuncAttributeMaxDynamicSharedMemorySize, (int)node_lds);
    (void)hipFuncSetAttribute((const void*)(rowmlp_kernel<64, false, false, true>),
                              hipFuncAttributeMaxDynamicSharedMemorySize, (int)ro_lds);

    hipMemsetAsync(gsum, 0, (size_t)GG * 64 * sizeof(float), stream);
    proj_kernel<<<(NN * 64 + 255) / 256, 256, 0, stream>>>(x, proj_w, proj_b, h, NN);

    const int etiles = EE / 128;               // 6250
    const int ntiles = (NN + 127) / 128;       // 391
    for (int l = 0; l < LL; ++l) {
        hipMemsetAsync(agg, 0, (size_t)NN * 64 * sizeof(float), stream);
        edge_kernel<<<250, 512, edge_lds, stream>>>(  // 250 blocks x exactly 25 tiles
            h, ei, ew1 + l * 8192, eb1 + l * 64, ew2 + l * 4096, eb2 + l * 64,
            agg, etiles);
        rowmlp_kernel<128, false, true, false><<<196, 512, node_lds, stream>>>(
            h, agg, nw1 + l * 8192, nb1 + l * 64, nw2 + l * 4096, nb2 + l * 64,
            nullptr, h, NN, ntiles);
    }
    rowmlp_kernel<64, false, false, true><<<196, 512, ro_lds, stream>>>(
        h, nullptr, l1w, l1b, l2w, l2b, batch, gsum, NN, ntiles);
    head_kernel<<<GG / 4, 256, 0, stream>>>(gsum, l3w, l3b, l4w, l4b, out, GG);
}

// Round 3
// 1580.077 us; speedup vs baseline: 2.9169x; 2.9169x over previous
//
#include <hip/hip_runtime.h>

#define NN 50000
#define EE 800000
#define GG 512
#define LL 3

__device__ __forceinline__ float silu_f(float x) {
    return x * __builtin_amdgcn_rcpf(1.0f + __expf(-x));
}

// ===========================================================================
// CSR build: histogram -> exclusive scan -> scatter into dst-sorted arrays
// ===========================================================================
__global__ __launch_bounds__(256) void hist_kernel(const int* __restrict__ ei,
                                                   int* __restrict__ deg) {
    int e = blockIdx.x * 256 + threadIdx.x;
    if (e < EE) atomicAdd(&deg[ei[EE + e]], 1);
}

__global__ __launch_bounds__(1024) void scan_kernel(const int* __restrict__ deg,
                                                    int* __restrict__ rowptr,
                                                    int* __restrict__ cursor) {
    __shared__ int wsum[16];
    __shared__ int sCarry;
    const int tid = threadIdx.x;
    const int lane = tid & 63, wid = tid >> 6;
    if (tid == 0) sCarry = 0;
    __syncthreads();
    for (int base = 0; base < NN; base += 1024) {
        int i = base + tid;
        int v = (i < NN) ? deg[i] : 0;
        int x = v;  // inclusive wave scan
#pragma unroll
        for (int s = 1; s < 64; s <<= 1) {
            int u = __shfl_up(x, s, 64);
            if (lane >= s) x += u;
        }
        if (lane == 63) wsum[wid] = x;
        __syncthreads();
        int woff = 0;
        for (int w = 0; w < wid; ++w) woff += wsum[w];
        int carry = sCarry;
        int excl = carry + woff + x - v;
        if (i < NN) { rowptr[i] = excl; cursor[i] = excl; }
        __syncthreads();
        if (tid == 1023) sCarry = carry + woff + x;
        __syncthreads();
    }
    if (tid == 0) rowptr[NN] = sCarry;
}

__global__ __launch_bounds__(256) void scatter_kernel(const int* __restrict__ ei,
                                                      int* __restrict__ cursor,
                                                      int* __restrict__ srcsS,
                                                      int* __restrict__ dstsS) {
    int e = blockIdx.x * 256 + threadIdx.x;
    if (e < EE) {
        int d = ei[EE + e];
        int pos = atomicAdd(&cursor[d], 1);
        srcsS[pos] = ei[e];
        dstsS[pos] = d;
    }
}

// ===========================================================================
// Edge-message kernel over DST-SORTED edges. Per 128-edge tile:
//   cat = [h[dst], h[src]] ; m = silu(silu(cat@W1+b1)@W2+b2)
//   then 32-lane shuffle segmented-reduce over sorted dst runs; only segment
//   tails atomicAdd into agg (~640 atomics/tile vs 8192 naive).
// ===========================================================================
__global__ __launch_bounds__(512, 1) void edge_kernel(
    const float* __restrict__ h,
    const int* __restrict__ srcsS, const int* __restrict__ dstsS,
    const float* __restrict__ w1g, const float* __restrict__ b1g,
    const float* __restrict__ w2g, const float* __restrict__ b2g,
    float* __restrict__ agg, int ntiles)
{
    extern __shared__ float lds[];
    float* ws1  = lds;               // 128*64
    float* ws2  = ws1 + 8192;        // 64*64
    float* wb1  = ws2 + 4096;
    float* wb2  = wb1 + 64;
    float* cats = wb2 + 64;          // 128 * 132
    float* m1s  = cats + 128 * 132;  // 128 * 68
    int*   dsts = (int*)(m1s + 128 * 68);  // 128
    int*   srcs = dsts + 128;              // 128

    const int tid = threadIdx.x;
    const int tr  = tid & 31;
    const int tc  = tid >> 5;

    for (int i = tid; i < 2048; i += 512)
        *(float4*)&ws1[4 * i] = *(const float4*)&w1g[4 * i];
    for (int i = tid; i < 1024; i += 512)
        *(float4*)&ws2[4 * i] = *(const float4*)&w2g[4 * i];
    if (tid < 64) { wb1[tid] = b1g[tid]; wb2[tid] = b2g[tid]; }

    for (int tile = blockIdx.x; tile < ntiles; tile += gridDim.x) {
        const int ebase = tile * 128;
        __syncthreads();  // prior iter LDS reads complete
        if (tid < 128)      dsts[tid]       = dstsS[ebase + tid];
        else if (tid < 256) srcs[tid - 128] = srcsS[ebase + tid - 128];
        __syncthreads();
#pragma unroll
        for (int rep = 0; rep < 8; ++rep) {
            int idx = rep * 512 + tid;
            int e = idx >> 5, q = idx & 31;
            const float* p = (q < 16) ? (h + 64 * dsts[e] + 4 * q)
                                      : (h + 64 * srcs[e] + 4 * (q - 16));
            *(float4*)&cats[e * 132 + 4 * q] = *(const float4*)p;
        }
        __syncthreads();
        // ---- stage 1 ----
        float acc[4][4];
#pragma unroll
        for (int jj = 0; jj < 4; ++jj)
#pragma unroll
            for (int ii = 0; ii < 4; ++ii) acc[jj][ii] = wb1[4 * tc + ii];
#pragma unroll 4
        for (int k16 = 0; k16 < 32; ++k16) {
            float4 bv0 = *(const float4*)&ws1[(4 * k16 + 0) * 64 + 4 * tc];
            float4 bv1 = *(const float4*)&ws1[(4 * k16 + 1) * 64 + 4 * tc];
            float4 bv2 = *(const float4*)&ws1[(4 * k16 + 2) * 64 + 4 * tc];
            float4 bv3 = *(const float4*)&ws1[(4 * k16 + 3) * 64 + 4 * tc];
#pragma unroll
            for (int jj = 0; jj < 4; ++jj) {
                float4 av = *(const float4*)&cats[(tr + 32 * jj) * 132 + 4 * k16];
                acc[jj][0] = fmaf(av.x, bv0.x, fmaf(av.y, bv1.x, fmaf(av.z, bv2.x, fmaf(av.w, bv3.x, acc[jj][0]))));
                acc[jj][1] = fmaf(av.x, bv0.y, fmaf(av.y, bv1.y, fmaf(av.z, bv2.y, fmaf(av.w, bv3.y, acc[jj][1]))));
                acc[jj][2] = fmaf(av.x, bv0.z, fmaf(av.y, bv1.z, fmaf(av.z, bv2.z, fmaf(av.w, bv3.z, acc[jj][2]))));
                acc[jj][3] = fmaf(av.x, bv0.w, fmaf(av.y, bv1.w, fmaf(av.z, bv2.w, fmaf(av.w, bv3.w, acc[jj][3]))));
            }
        }
#pragma unroll
        for (int jj = 0; jj < 4; ++jj) {
            float4 v;
            v.x = silu_f(acc[jj][0]); v.y = silu_f(acc[jj][1]);
            v.z = silu_f(acc[jj][2]); v.w = silu_f(acc[jj][3]);
            *(float4*)&m1s[(tr + 32 * jj) * 68 + 4 * tc] = v;
        }
        __syncthreads();
        // ---- stage 2 ----
        float acc2[4][4];
#pragma unroll
        for (int jj = 0; jj < 4; ++jj)
#pragma unroll
            for (int ii = 0; ii < 4; ++ii) acc2[jj][ii] = wb2[4 * tc + ii];
#pragma unroll 4
        for (int k16 = 0; k16 < 16; ++k16) {
            float4 bv0 = *(const float4*)&ws2[(4 * k16 + 0) * 64 + 4 * tc];
            float4 bv1 = *(const float4*)&ws2[(4 * k16 + 1) * 64 + 4 * tc];
            float4 bv2 = *(const float4*)&ws2[(4 * k16 + 2) * 64 + 4 * tc];
            float4 bv3 = *(const float4*)&ws2[(4 * k16 + 3) * 64 + 4 * tc];
#pragma unroll
            for (int jj = 0; jj < 4; ++jj) {
                float4 av = *(const float4*)&m1s[(tr + 32 * jj) * 68 + 4 * k16];
                acc2[jj][0] = fmaf(av.x, bv0.x, fmaf(av.y, bv1.x, fmaf(av.z, bv2.x, fmaf(av.w, bv3.x, acc2[jj][0]))));
                acc2[jj][1] = fmaf(av.x, bv0.y, fmaf(av.y, bv1.y, fmaf(av.z, bv2.y, fmaf(av.w, bv3.y, acc2[jj][1]))));
                acc2[jj][2] = fmaf(av.x, bv0.z, fmaf(av.y, bv1.z, fmaf(av.z, bv2.z, fmaf(av.w, bv3.z, acc2[jj][2]))));
                acc2[jj][3] = fmaf(av.x, bv0.w, fmaf(av.y, bv1.w, fmaf(av.z, bv2.w, fmaf(av.w, bv3.w, acc2[jj][3]))));
            }
        }
        // ---- segmented reduce over sorted dsts, flush tails only ----
#pragma unroll
        for (int jj = 0; jj < 4; ++jj) {
            int r = 32 * jj + tr;
            int d = dsts[r];
            float4 v;
            v.x = silu_f(acc2[jj][0]); v.y = silu_f(acc2[jj][1]);
            v.z = silu_f(acc2[jj][2]); v.w = silu_f(acc2[jj][3]);
            unsigned f = (tr == 0 || dsts[r - 1] != d) ? 1u : 0u;
#pragma unroll
            for (int s = 1; s < 32; s <<= 1) {
                float ux = __shfl_up(v.x, s, 32);
                float uy = __shfl_up(v.y, s, 32);
                float uz = __shfl_up(v.z, s, 32);
                float uw = __shfl_up(v.w, s, 32);
                unsigned uf = __shfl_up(f, s, 32);
                if (tr >= s) {
                    if (!f) { v.x += ux; v.y += uy; v.z += uz; v.w += uw; }
                    f |= uf;
                }
            }
            bool tail = (tr == 31) || (dsts[r + 1] != d);
            if (tail) {
                float* bp = agg + 64 * d + 4 * tc;
                atomicAdd(bp + 0, v.x); atomicAdd(bp + 1, v.y);
                atomicAdd(bp + 2, v.z); atomicAdd(bp + 3, v.w);
            }
        }
    }
}

// ===========================================================================
// Row-MLP kernel (node update / readout). SCATTER path uses the same
// segmented reduction (batch ids are sorted in the input).
// ===========================================================================
template <int K1, bool SILU2, bool RESID, bool SCATTER>
__global__ __launch_bounds__(512, 1) void rowmlp_kernel(
    const float* __restrict__ A, const float* __restrict__ A2,
    const float* __restrict__ w1g, const float* __restrict__ b1g,
    const float* __restrict__ w2g, const float* __restrict__ b2g,
    const int* __restrict__ seg, float* __restrict__ outp,
    int nrows, int ntiles)
{
    constexpr int CST = K1 + 4;
    constexpr int QN  = K1 / 4;
    constexpr int QSH = (K1 == 128) ? 5 : 4;
    constexpr int REPS = QN / 4;

    extern __shared__ float lds[];
    float* ws1  = lds;
    float* ws2  = ws1 + K1 * 64;
    float* wb1  = ws2 + 4096;
    float* wb2  = wb1 + 64;
    float* cats = wb2 + 64;
    float* m1s  = cats + 128 * CST;
    int*   segs = (int*)(m1s + 128 * 68);

    const int tid = threadIdx.x;
    const int tr  = tid & 31;
    const int tc  = tid >> 5;

    for (int i = tid; i < K1 * 16; i += 512)
        *(float4*)&ws1[4 * i] = *(const float4*)&w1g[4 * i];
    for (int i = tid; i < 1024; i += 512)
        *(float4*)&ws2[4 * i] = *(const float4*)&w2g[4 * i];
    if (tid < 64) { wb1[tid] = b1g[tid]; wb2[tid] = b2g[tid]; }

    for (int tile = blockIdx.x; tile < ntiles; tile += gridDim.x) {
        const int base = tile * 128;
        __syncthreads();
        if (SCATTER) {
            if (tid < 128) segs[tid] = (base + tid < nrows) ? seg[base + tid] : -1;
        }
#pragma unroll
        for (int rep = 0; rep < REPS; ++rep) {
            int idx = rep * 512 + tid;
            int r = idx >> QSH, q = idx & (QN - 1);
            int n = base + r;
            float4 v = make_float4(0.f, 0.f, 0.f, 0.f);
            if (n < nrows) {
                if constexpr (K1 == 128)
                    v = (q < 16) ? *(const float4*)(A + 64 * n + 4 * q)
                                 : *(const float4*)(A2 + 64 * n + 4 * (q - 16));
                else
                    v = *(const float4*)(A + 64 * n + 4 * q);
            }
            *(float4*)&cats[r * CST + 4 * q] = v;
        }
        __syncthreads();
        float acc[4][4];
#pragma unroll
        for (int jj = 0; jj < 4; ++jj)
#pragma unroll
            for (int ii = 0; ii < 4; ++ii) acc[jj][ii] = wb1[4 * tc + ii];
#pragma unroll 4
        for (int k16 = 0; k16 < K1 / 4; ++k16) {
            float4 bv0 = *(const float4*)&ws1[(4 * k16 + 0) * 64 + 4 * tc];
            float4 bv1 = *(const float4*)&ws1[(4 * k16 + 1) * 64 + 4 * tc];
            float4 bv2 = *(const float4*)&ws1[(4 * k16 + 2) * 64 + 4 * tc];
            float4 bv3 = *(const float4*)&ws1[(4 * k16 + 3) * 64 + 4 * tc];
#pragma unroll
            for (int jj = 0; jj < 4; ++jj) {
                float4 av = *(const float4*)&cats[(tr + 32 * jj) * CST + 4 * k16];
                acc[jj][0] = fmaf(av.x, bv0.x, fmaf(av.y, bv1.x, fmaf(av.z, bv2.x, fmaf(av.w, bv3.x, acc[jj][0]))));
                acc[jj][1] = fmaf(av.x, bv0.y, fmaf(av.y, bv1.y, fmaf(av.z, bv2.y, fmaf(av.w, bv3.y, acc[jj][1]))));
                acc[jj][2] = fmaf(av.x, bv0.z, fmaf(av.y, bv1.z, fmaf(av.z, bv2.z, fmaf(av.w, bv3.z, acc[jj][2]))));
                acc[jj][3] = fmaf(av.x, bv0.w, fmaf(av.y, bv1.w, fmaf(av.z, bv2.w, fmaf(av.w, bv3.w, acc[jj][3]))));
            }
        }
#pragma unroll
        for (int jj = 0; jj < 4; ++jj) {
            float4 v;
            v.x = silu_f(acc[jj][0]); v.y = silu_f(acc[jj][1]);
            v.z = silu_f(acc[jj][2]); v.w = silu_f(acc[jj][3]);
            *(float4*)&m1s[(tr + 32 * jj) * 68 + 4 * tc] = v;
        }
        __syncthreads();
        float acc2[4][4];
#pragma unroll
        for (int jj = 0; jj < 4; ++jj)
#pragma unroll
            for (int ii = 0; ii < 4; ++ii) acc2[jj][ii] = wb2[4 * tc + ii];
#pragma unroll 4
        for (int k16 = 0; k16 < 16; ++k16) {
            float4 bv0 = *(const float4*)&ws2[(4 * k16 + 0) * 64 + 4 * tc];
            float4 bv1 = *(const float4*)&ws2[(4 * k16 + 1) * 64 + 4 * tc];
            float4 bv2 = *(const float4*)&ws2[(4 * k16 + 2) * 64 + 4 * tc];
            float4 bv3 = *(const float4*)&ws2[(4 * k16 + 3) * 64 + 4 * tc];
#pragma unroll
            for (int jj = 0; jj < 4; ++jj) {
                float4 av = *(const float4*)&m1s[(tr + 32 * jj) * 68 + 4 * k16];
                acc2[jj][0] = fmaf(av.x, bv0.x, fmaf(av.y, bv1.x, fmaf(av.z, bv2.x, fmaf(av.w, bv3.x, acc2[jj][0]))));
                acc2[jj][1] = fmaf(av.x, bv0.y, fmaf(av.y, bv1.y, fmaf(av.z, bv2.y, fmaf(av.w, bv3.y, acc2[jj][1]))));
                acc2[jj][2] = fmaf(av.x, bv0.z, fmaf(av.y, bv1.z, fmaf(av.z, bv2.z, fmaf(av.w, bv3.z, acc2[jj][2]))));
                acc2[jj][3] = fmaf(av.x, bv0.w, fmaf(av.y, bv1.w, fmaf(av.z, bv2.w, fmaf(av.w, bv3.w, acc2[jj][3]))));
            }
        }
#pragma unroll
        for (int jj = 0; jj < 4; ++jj) {
            int r = tr + 32 * jj;
            int n = base + r;
            float v[4];
#pragma unroll
            for (int ii = 0; ii < 4; ++ii)
                v[ii] = SILU2 ? silu_f(acc2[jj][ii]) : acc2[jj][ii];
            if (RESID) {
                float4 hold = *(const float4*)&cats[r * CST + 4 * tc];
                v[0] += hold.x; v[1] += hold.y; v[2] += hold.z; v[3] += hold.w;
            }
            if (SCATTER) {
                int gid = segs[r];
                float4 vv = (n < nrows) ? make_float4(v[0], v[1], v[2], v[3])
                                        : make_float4(0.f, 0.f, 0.f, 0.f);
                unsigned f = (tr == 0 || segs[r - 1] != gid) ? 1u : 0u;
#pragma unroll
                for (int s = 1; s < 32; s <<= 1) {
                    float ux = __shfl_up(vv.x, s, 32);
                    float uy = __shfl_up(vv.y, s, 32);
                    float uz = __shfl_up(vv.z, s, 32);
                    float uw = __shfl_up(vv.w, s, 32);
                    unsigned uf = __shfl_up(f, s, 32);
                    if (tr >= s) {
                        if (!f) { vv.x += ux; vv.y += uy; vv.z += uz; vv.w += uw; }
                        f |= uf;
                    }
                }
                bool tail = (tr == 31) || (segs[r + 1] != gid);
                if (tail && gid >= 0) {
                    float* bp = outp + 64 * gid + 4 * tc;
                    atomicAdd(bp + 0, vv.x); atomicAdd(bp + 1, vv.y);
                    atomicAdd(bp + 2, vv.z); atomicAdd(bp + 3, vv.w);
                }
            } else if (n < nrows) {
                *(float4*)&outp[64 * n + 4 * tc] = make_float4(v[0], v[1], v[2], v[3]);
            }
        }
    }
}

__global__ __launch_bounds__(256) void proj_kernel(
    const float* __restrict__ x, const float* __restrict__ w,
    const float* __restrict__ b, float* __restrict__ h, int n)
{
    int i = blockIdx.x * 256 + threadIdx.x;
    if (i >= n * 64) return;
    int node = i >> 6, j = i & 63;
    const float* xr = x + node * 14;
    float acc = b[j];
#pragma unroll
    for (int k = 0; k < 14; ++k) acc = fmaf(xr[k], w[k * 64 + j], acc);
    h[i] = acc;
}

__global__ __launch_bounds__(256) void head_kernel(
    const float* __restrict__ gsum,
    const float* __restrict__ w3, const float* __restrict__ b3,
    const float* __restrict__ w4, const float* __restrict__ b4,
    float* __restrict__ out, int g_count)
{
    int wid  = (blockIdx.x * 256 + threadIdx.x) >> 6;
    int lane = threadIdx.x & 63;
    if (wid >= g_count) return;
    float v = gsum[wid * 64 + lane];
    float t = b3[lane];
#pragma unroll
    for (int k = 0; k < 64; ++k) {
        float a = __shfl(v, k, 64);
        t = fmaf(a, w3[k * 64 + lane], t);
    }
    t = silu_f(t);
    float r = t * w4[lane];
#pragma unroll
    for (int off = 32; off; off >>= 1) r += __shfl_down(r, off, 64);
    if (lane == 0) out[wid] = r + b4[0];
}

extern "C" void kernel_launch(void* const* d_in, const int* in_sizes, int n_in,
                              void* d_out, int out_size, void* d_ws, size_t ws_size,
                              hipStream_t stream)
{
    const float* x      = (const float*)d_in[0];
    const int*   ei     = (const int*)d_in[2];
    const int*   batch  = (const int*)d_in[3];
    const float* proj_w = (const float*)d_in[4];
    const float* proj_b = (const float*)d_in[5];
    const float* ew1 = (const float*)d_in[6];
    const float* eb1 = (const float*)d_in[7];
    const float* ew2 = (const float*)d_in[8];
    const float* eb2 = (const float*)d_in[9];
    const float* nw1 = (const float*)d_in[10];
    const float* nb1 = (const float*)d_in[11];
    const float* nw2 = (const float*)d_in[12];
    const float* nb2 = (const float*)d_in[13];
    const float* l1w = (const float*)d_in[14]; const float* l1b = (const float*)d_in[15];
    const float* l2w = (const float*)d_in[16]; const float* l2b = (const float*)d_in[17];
    const float* l3w = (const float*)d_in[18]; const float* l3b = (const float*)d_in[19];
    const float* l4w = (const float*)d_in[20]; const float* l4b = (const float*)d_in[21];

    float* out  = (float*)d_out;
    float* h    = out + GG;                      // per_atom_out doubles as h

    float* agg  = (float*)d_ws;                  // [N,64]
    float* gsum = agg + (size_t)NN * 64;         // [G,64]
    int* deg    = (int*)(gsum + (size_t)GG * 64);
    int* rowptr = deg + NN;                      // N+1
    int* cursor = rowptr + NN + 1;
    int* srcsS  = cursor + NN;                   // [E]
    int* dstsS  = srcsS + EE;                    // [E]

    const size_t edge_lds = (size_t)(8192 + 4096 + 128 + 128 * 132 + 128 * 68) * 4 + 256 * 4;
    const size_t node_lds = (size_t)(8192 + 4096 + 128 + 128 * 132 + 128 * 68) * 4 + 128 * 4;
    const size_t ro_lds   = (size_t)(4096 + 4096 + 128 + 128 * 68 + 128 * 68) * 4 + 128 * 4;

    (void)hipFuncSetAttribute((const void*)edge_kernel,
                              hipFuncAttributeMaxDynamicSharedMemorySize, (int)edge_lds);
    (void)hipFuncSetAttribute((const void*)(rowmlp_kernel<128, false, true, false>),
                              hipFuncAttributeMaxDynamicSharedMemorySize, (int)node_lds);
    (void)hipFuncSetAttribute((const void*)(rowmlp_kernel<64, false, false, true>),
                              hipFuncAttributeMaxDynamicSharedMemorySize, (int)ro_lds);

    // --- CSR build (dst-sorted edge arrays), per call ---
    hipMemsetAsync(deg, 0, (size_t)NN * sizeof(int), stream);
    hipMemsetAsync(gsum, 0, (size_t)GG * 64 * sizeof(float), stream);
    hist_kernel<<<(EE + 255) / 256, 256, 0, stream>>>(ei, deg);
    scan_kernel<<<1, 1024, 0, stream>>>(deg, rowptr, cursor);
    scatter_kernel<<<(EE + 255) / 256, 256, 0, stream>>>(ei, cursor, srcsS, dstsS);

    proj_kernel<<<(NN * 64 + 255) / 256, 256, 0, stream>>>(x, proj_w, proj_b, h, NN);

    const int etiles = EE / 128;               // 6250
    const int ntiles = (NN + 127) / 128;       // 391
    for (int l = 0; l < LL; ++l) {
        hipMemsetAsync(agg, 0, (size_t)NN * 64 * sizeof(float), stream);
        edge_kernel<<<250, 512, edge_lds, stream>>>(
            h, srcsS, dstsS, ew1 + l * 8192, eb1 + l * 64, ew2 + l * 4096, eb2 + l * 64,
            agg, etiles);
        rowmlp_kernel<128, false, true, false><<<196, 512, node_lds, stream>>>(
            h, agg, nw1 + l * 8192, nb1 + l * 64, nw2 + l * 4096, nb2 + l * 64,
            nullptr, h, NN, ntiles);
    }
    rowmlp_kernel<64, false, false, true><<<196, 512, ro_lds, stream>>>(
        h, nullptr, l1w, l1b, l2w, l2b, batch, gsum, NN, ntiles);
    head_kernel<<<GG / 4, 256, 0, stream>>>(gsum, l3w, l3b, l4w, l4b, out, GG);
}

// Round 4
// 987.726 us; speedup vs baseline: 4.6661x; 1.5997x over previous
//
#include <hip/hip_runtime.h>

#define NN 50000
#define EE 800000
#define GG 512
#define LL 3

typedef short bf16x8 __attribute__((ext_vector_type(8)));
typedef float f32x4  __attribute__((ext_vector_type(4)));

__device__ __forceinline__ float silu_f(float x) {
    return x * __builtin_amdgcn_rcpf(1.0f + __expf(-x));
}

__device__ __forceinline__ unsigned short bf16_rne(float x) {
    unsigned u = __float_as_uint(x);
    u += 0x7fffu + ((u >> 16) & 1u);
    return (unsigned short)(u >> 16);
}
__device__ __forceinline__ float bf16_to_f(unsigned short b) {
    return __uint_as_float(((unsigned)b) << 16);
}
__device__ __forceinline__ f32x4 mfma16(bf16x8 a, bf16x8 b, f32x4 c) {
    return __builtin_amdgcn_mfma_f32_16x16x32_bf16(a, b, c, 0, 0, 0);
}

// ===========================================================================
// CSR build: histogram -> exclusive scan -> scatter into dst-sorted arrays
// ===========================================================================
__global__ __launch_bounds__(256) void hist_kernel(const int* __restrict__ ei,
                                                   int* __restrict__ deg) {
    int e = blockIdx.x * 256 + threadIdx.x;
    if (e < EE) atomicAdd(&deg[ei[EE + e]], 1);
}

__global__ __launch_bounds__(1024) void scan_kernel(const int* __restrict__ deg,
                                                    int* __restrict__ rowptr,
                                                    int* __restrict__ cursor) {
    __shared__ int wsum[16];
    __shared__ int sCarry;
    const int tid = threadIdx.x;
    const int lane = tid & 63, wid = tid >> 6;
    if (tid == 0) sCarry = 0;
    __syncthreads();
    for (int base = 0; base < NN; base += 1024) {
        int i = base + tid;
        int v = (i < NN) ? deg[i] : 0;
        int x = v;
#pragma unroll
        for (int s = 1; s < 64; s <<= 1) {
            int u = __shfl_up(x, s, 64);
            if (lane >= s) x += u;
        }
        if (lane == 63) wsum[wid] = x;
        __syncthreads();
        int woff = 0;
        for (int w = 0; w < wid; ++w) woff += wsum[w];
        int carry = sCarry;
        int excl = carry + woff + x - v;
        if (i < NN) { rowptr[i] = excl; cursor[i] = excl; }
        __syncthreads();
        if (tid == 1023) sCarry = carry + woff + x;
        __syncthreads();
    }
    if (tid == 0) rowptr[NN] = sCarry;
}

__global__ __launch_bounds__(256) void scatter_kernel(const int* __restrict__ ei,
                                                      int* __restrict__ cursor,
                                                      int* __restrict__ srcsS,
                                                      int* __restrict__ dstsS) {
    int e = blockIdx.x * 256 + threadIdx.x;
    if (e < EE) {
        int d = ei[EE + e];
        int pos = atomicAdd(&cursor[d], 1);
        srcsS[pos] = ei[e];
        dstsS[pos] = d;
    }
}

// ===========================================================================
// MFMA edge kernel over DST-SORTED edges. 128-edge tiles, 512 threads/8 waves.
// Wave w: mi=w>>1 (rows 32mi..+31), ni=w&1 (cols 32ni..+31); 2x2 16x16 frags.
// Stage1: split-bf16 (hi+lo, 3 MFMA) == fp32-grade. Stage2: plain bf16.
// LDS tiles bf16 with XOR swizzle byte^=((row&15)<<4) on 256B rows.
// m2 staged to f32 LDS; segmented shuffle-scan + tail atomics (round-3 proven).
// ===========================================================================
__global__ __launch_bounds__(512, 1) void edge_kernel(
    const float* __restrict__ h,
    const int* __restrict__ srcsS, const int* __restrict__ dstsS,
    const float* __restrict__ w1g, const float* __restrict__ b1g,
    const float* __restrict__ w2g, const float* __restrict__ b2g,
    float* __restrict__ agg, int ntiles)
{
    extern __shared__ __align__(16) char smem[];
    char*  wt1h = smem;                    // [64 col][256B k]   16384
    char*  wt1l = wt1h + 16384;            //                    16384
    char*  wt2s = wt1l + 16384;            // [64 col][256B pad] 16384
    char*  cath = wt2s + 16384;            // [128 row][256B k]  32768
    char*  catl = cath + 32768;            //                    32768
    float* m1f  = (float*)(catl + 32768);  // [128][68] f32 (also m2)  34816
    float* b1s  = (float*)((char*)m1f + 34816);  // 64
    float* b2s  = b1s + 64;                      // 64
    int*   dstsL = (int*)(b2s + 64);             // 128

    const int tid = threadIdx.x;
    const int l   = tid & 63;
    const int w   = tid >> 6;
    const int mi  = w >> 1;
    const int ni  = w & 1;
    const int l15 = l & 15;
    const int l4  = l >> 4;
    const int swz = l15 << 4;

    // ---- stage weights once per block ----
    for (int i = tid; i < 1024; i += 512) {       // Wt1 hi/lo: transpose + split
        int c = i >> 4, kc = i & 15;
        const float* wp = w1g + (kc * 8) * 64 + c;
        bf16x8 hi, lo;
#pragma unroll
        for (int j = 0; j < 8; ++j) {
            float v = wp[j * 64];
            unsigned short hb = bf16_rne(v);
            hi[j] = (short)hb;
            lo[j] = (short)bf16_rne(v - bf16_to_f(hb));
        }
        int off = c * 256 + ((kc * 16) ^ ((c & 15) << 4));
        *(bf16x8*)(wt1h + off) = hi;
        *(bf16x8*)(wt1l + off) = lo;
    }
    {                                             // Wt2: transpose, plain bf16
        int c = tid >> 3, kc = tid & 7;
        const float* wp = w2g + (kc * 8) * 64 + c;
        bf16x8 hi;
#pragma unroll
        for (int j = 0; j < 8; ++j) hi[j] = (short)bf16_rne(wp[j * 64]);
        int off = c * 256 + ((kc * 16) ^ ((c & 15) << 4));
        *(bf16x8*)(wt2s + off) = hi;
    }
    if (tid < 64) { b1s[tid] = b1g[tid]; b2s[tid] = b2g[tid]; }

    for (int tile = blockIdx.x; tile < ntiles; tile += gridDim.x) {
        const int ebase = tile * 128;
        __syncthreads();                          // prev-tile LDS reads done
        if (tid < 128) dstsL[tid] = dstsS[ebase + tid];
        // ---- gather cat rows, convert to split bf16, write swizzled ----
#pragma unroll
        for (int rep = 0; rep < 4; ++rep) {
            int idx = rep * 512 + tid;            // 2048 16B-chunks
            int e = idx >> 4, q = idx & 15;       // row, chunk-in-row
            int node = (q < 8) ? dstsS[ebase + e] : srcsS[ebase + e];
            const float* p = h + 64 * node + (q & 7) * 8;
            float4 va = *(const float4*)p;
            float4 vb = *(const float4*)(p + 4);
            float vv[8] = {va.x, va.y, va.z, va.w, vb.x, vb.y, vb.z, vb.w};
            bf16x8 hi, lo;
#pragma unroll
            for (int j = 0; j < 8; ++j) {
                unsigned short hb = bf16_rne(vv[j]);
                hi[j] = (short)hb;
                lo[j] = (short)bf16_rne(vv[j] - bf16_to_f(hb));
            }
            int off = e * 256 + ((q * 16) ^ ((e & 15) << 4));
            *(bf16x8*)(cath + off) = hi;
            *(bf16x8*)(catl + off) = lo;
        }
        __syncthreads();
        // ---- stage 1: cat[128x128] @ W1[128x64], split-bf16 ----
        f32x4 acc[2][2];
#pragma unroll
        for (int m = 0; m < 2; ++m)
#pragma unroll
            for (int n = 0; n < 2; ++n) {
                float b = b1s[32 * ni + 16 * n + l15];
                acc[m][n] = (f32x4){b, b, b, b};
            }
#pragma unroll
        for (int ks = 0; ks < 4; ++ks) {
            int kb = ks * 64 + l4 * 16;
            int ko = kb ^ swz;
            bf16x8 ah[2], al[2], bh[2], bl[2];
#pragma unroll
            for (int m = 0; m < 2; ++m) {
                int off = (32 * mi + 16 * m + l15) * 256 + ko;
                ah[m] = *(const bf16x8*)(cath + off);
                al[m] = *(const bf16x8*)(catl + off);
            }
#pragma unroll
            for (int n = 0; n < 2; ++n) {
                int off = (32 * ni + 16 * n + l15) * 256 + ko;
                bh[n] = *(const bf16x8*)(wt1h + off);
                bl[n] = *(const bf16x8*)(wt1l + off);
            }
#pragma unroll
            for (int m = 0; m < 2; ++m)
#pragma unroll
                for (int n = 0; n < 2; ++n) {
                    acc[m][n] = mfma16(ah[m], bh[n], acc[m][n]);
                    acc[m][n] = mfma16(ah[m], bl[n], acc[m][n]);
                    acc[m][n] = mfma16(al[m], bh[n], acc[m][n]);
                }
        }
        // m1 = silu(acc) -> f32 LDS  (C/D: col=lane&15, row=(lane>>4)*4+reg)
#pragma unroll
        for (int m = 0; m < 2; ++m)
#pragma unroll
            for (int n = 0; n < 2; ++n)
#pragma unroll
                for (int r = 0; r < 4; ++r) {
                    int row = 32 * mi + 16 * m + l4 * 4 + r;
                    m1f[row * 68 + 32 * ni + 16 * n + l15] = silu_f(acc[m][n][r]);
                }
        __syncthreads();
        // ---- stage 2: m1[128x64] @ W2[64x64], plain bf16 ----
        f32x4 acc2[2][2];
#pragma unroll
        for (int m = 0; m < 2; ++m)
#pragma unroll
            for (int n = 0; n < 2; ++n) {
                float b = b2s[32 * ni + 16 * n + l15];
                acc2[m][n] = (f32x4){b, b, b, b};
            }
#pragma unroll
        for (int ks = 0; ks < 2; ++ks) {
            bf16x8 af[2];
#pragma unroll
            for (int m = 0; m < 2; ++m) {
                const float* ap = m1f + (32 * mi + 16 * m + l15) * 68 + ks * 32 + l4 * 8;
                float4 a0 = *(const float4*)ap;
                float4 a1 = *(const float4*)(ap + 4);
                float avv[8] = {a0.x, a0.y, a0.z, a0.w, a1.x, a1.y, a1.z, a1.w};
#pragma unroll
                for (int j = 0; j < 8; ++j) af[m][j] = (short)bf16_rne(avv[j]);
            }
            int kb = ks * 64 + l4 * 16;
            bf16x8 bf2[2];
#pragma unroll
            for (int n = 0; n < 2; ++n)
                bf2[n] = *(const bf16x8*)(wt2s + (32 * ni + 16 * n + l15) * 256 + (kb ^ swz));
#pragma unroll
            for (int m = 0; m < 2; ++m)
#pragma unroll
                for (int n = 0; n < 2; ++n)
                    acc2[m][n] = mfma16(af[m], bf2[n], acc2[m][n]);
        }
        __syncthreads();                          // all m1f reads done
        // m2 = silu(acc2) -> same f32 LDS buffer
#pragma unroll
        for (int m = 0; m < 2; ++m)
#pragma unroll
            for (int n = 0; n < 2; ++n)
#pragma unroll
                for (int r = 0; r < 4; ++r) {
                    int row = 32 * mi + 16 * m + l4 * 4 + r;
                    m1f[row * 68 + 32 * ni + 16 * n + l15] = silu_f(acc2[m][n][r]);
                }
        __syncthreads();
        // ---- segmented reduce over sorted dsts, flush tails only ----
        const int tr = tid & 31, tc = tid >> 5;
#pragma unroll
        for (int jj = 0; jj < 4; ++jj) {
            int r = 32 * jj + tr;
            int d = dstsL[r];
            float4 v = *(const float4*)&m1f[r * 68 + 4 * tc];
            unsigned f = (tr == 0 || dstsL[r - 1] != d) ? 1u : 0u;
#pragma unroll
            for (int s = 1; s < 32; s <<= 1) {
                float ux = __shfl_up(v.x, s, 32);
                float uy = __shfl_up(v.y, s, 32);
                float uz = __shfl_up(v.z, s, 32);
                float uw = __shfl_up(v.w, s, 32);
                unsigned uf = __shfl_up(f, s, 32);
                if (tr >= s) {
                    if (!f) { v.x += ux; v.y += uy; v.z += uz; v.w += uw; }
                    f |= uf;
                }
            }
            bool tail = (tr == 31) || (dstsL[r + 1] != d);
            if (tail) {
                float* bp = agg + 64 * d + 4 * tc;
                atomicAdd(bp + 0, v.x); atomicAdd(bp + 1, v.y);
                atomicAdd(bp + 2, v.z); atomicAdd(bp + 3, v.w);
            }
        }
    }
}

// ===========================================================================
// Row-MLP kernel (node update / readout) — unchanged from round 3 (fp32).
// ===========================================================================
template <int K1, bool SILU2, bool RESID, bool SCATTER>
__global__ __launch_bounds__(512, 1) void rowmlp_kernel(
    const float* __restrict__ A, const float* __restrict__ A2,
    const float* __restrict__ w1g, const float* __restrict__ b1g,
    const float* __restrict__ w2g, const float* __restrict__ b2g,
    const int* __restrict__ seg, float* __restrict__ outp,
    int nrows, int ntiles)
{
    constexpr int CST = K1 + 4;
    constexpr int QN  = K1 / 4;
    constexpr int QSH = (K1 == 128) ? 5 : 4;
    constexpr int REPS = QN / 4;

    extern __shared__ float lds[];
    float* ws1  = lds;
    float* ws2  = ws1 + K1 * 64;
    float* wb1  = ws2 + 4096;
    float* wb2  = wb1 + 64;
    float* cats = wb2 + 64;
    float* m1s  = cats + 128 * CST;
    int*   segs = (int*)(m1s + 128 * 68);

    const int tid = threadIdx.x;
    const int tr  = tid & 31;
    const int tc  = tid >> 5;

    for (int i = tid; i < K1 * 16; i += 512)
        *(float4*)&ws1[4 * i] = *(const float4*)&w1g[4 * i];
    for (int i = tid; i < 1024; i += 512)
        *(float4*)&ws2[4 * i] = *(const float4*)&w2g[4 * i];
    if (tid < 64) { wb1[tid] = b1g[tid]; wb2[tid] = b2g[tid]; }

    for (int tile = blockIdx.x; tile < ntiles; tile += gridDim.x) {
        const int base = tile * 128;
        __syncthreads();
        if (SCATTER) {
            if (tid < 128) segs[tid] = (base + tid < nrows) ? seg[base + tid] : -1;
        }
#pragma unroll
        for (int rep = 0; rep < REPS; ++rep) {
            int idx = rep * 512 + tid;
            int r = idx >> QSH, q = idx & (QN - 1);
            int n = base + r;
            float4 v = make_float4(0.f, 0.f, 0.f, 0.f);
            if (n < nrows) {
                if constexpr (K1 == 128)
                    v = (q < 16) ? *(const float4*)(A + 64 * n + 4 * q)
                                 : *(const float4*)(A2 + 64 * n + 4 * (q - 16));
                else
                    v = *(const float4*)(A + 64 * n + 4 * q);
            }
            *(float4*)&cats[r * CST + 4 * q] = v;
        }
        __syncthreads();
        float acc[4][4];
#pragma unroll
        for (int jj = 0; jj < 4; ++jj)
#pragma unroll
            for (int ii = 0; ii < 4; ++ii) acc[jj][ii] = wb1[4 * tc + ii];
#pragma unroll 4
        for (int k16 = 0; k16 < K1 / 4; ++k16) {
            float4 bv0 = *(const float4*)&ws1[(4 * k16 + 0) * 64 + 4 * tc];
            float4 bv1 = *(const float4*)&ws1[(4 * k16 + 1) * 64 + 4 * tc];
            float4 bv2 = *(const float4*)&ws1[(4 * k16 + 2) * 64 + 4 * tc];
            float4 bv3 = *(const float4*)&ws1[(4 * k16 + 3) * 64 + 4 * tc];
#pragma unroll
            for (int jj = 0; jj < 4; ++jj) {
                float4 av = *(const float4*)&cats[(tr + 32 * jj) * CST + 4 * k16];
                acc[jj][0] = fmaf(av.x, bv0.x, fmaf(av.y, bv1.x, fmaf(av.z, bv2.x, fmaf(av.w, bv3.x, acc[jj][0]))));
                acc[jj][1] = fmaf(av.x, bv0.y, fmaf(av.y, bv1.y, fmaf(av.z, bv2.y, fmaf(av.w, bv3.y, acc[jj][1]))));
                acc[jj][2] = fmaf(av.x, bv0.z, fmaf(av.y, bv1.z, fmaf(av.z, bv2.z, fmaf(av.w, bv3.z, acc[jj][2]))));
                acc[jj][3] = fmaf(av.x, bv0.w, fmaf(av.y, bv1.w, fmaf(av.z, bv2.w, fmaf(av.w, bv3.w, acc[jj][3]))));
            }
        }
#pragma unroll
        for (int jj = 0; jj < 4; ++jj) {
            float4 v;
            v.x = silu_f(acc[jj][0]); v.y = silu_f(acc[jj][1]);
            v.z = silu_f(acc[jj][2]); v.w = silu_f(acc[jj][3]);
            *(float4*)&m1s[(tr + 32 * jj) * 68 + 4 * tc] = v;
        }
        __syncthreads();
        float acc2[4][4];
#pragma unroll
        for (int jj = 0; jj < 4; ++jj)
#pragma unroll
            for (int ii = 0; ii < 4; ++ii) acc2[jj][ii] = wb2[4 * tc + ii];
#pragma unroll 4
        for (int k16 = 0; k16 < 16; ++k16) {
            float4 bv0 = *(const float4*)&ws2[(4 * k16 + 0) * 64 + 4 * tc];
            float4 bv1 = *(const float4*)&ws2[(4 * k16 + 1) * 64 + 4 * tc];
            float4 bv2 = *(const float4*)&ws2[(4 * k16 + 2) * 64 + 4 * tc];
            float4 bv3 = *(const float4*)&ws2[(4 * k16 + 3) * 64 + 4 * tc];
#pragma unroll
            for (int jj = 0; jj < 4; ++jj) {
                float4 av = *(const float4*)&m1s[(tr + 32 * jj) * 68 + 4 * k16];
                acc2[jj][0] = fmaf(av.x, bv0.x, fmaf(av.y, bv1.x, fmaf(av.z, bv2.x, fmaf(av.w, bv3.x, acc2[jj][0]))));
                acc2[jj][1] = fmaf(av.x, bv0.y, fmaf(av.y, bv1.y, fmaf(av.z, bv2.y, fmaf(av.w, bv3.y, acc2[jj][1]))));
                acc2[jj][2] = fmaf(av.x, bv0.z, fmaf(av.y, bv1.z, fmaf(av.z, bv2.z, fmaf(av.w, bv3.z, acc2[jj][2]))));
                acc2[jj][3] = fmaf(av.x, bv0.w, fmaf(av.y, bv1.w, fmaf(av.z, bv2.w, fmaf(av.w, bv3.w, acc2[jj][3]))));
            }
        }
#pragma unroll
        for (int jj = 0; jj < 4; ++jj) {
            int r = tr + 32 * jj;
            int n = base + r;
            float v[4];
#pragma unroll
            for (int ii = 0; ii < 4; ++ii)
                v[ii] = SILU2 ? silu_f(acc2[jj][ii]) : acc2[jj][ii];
            if (RESID) {
                float4 hold = *(const float4*)&cats[r * CST + 4 * tc];
                v[0] += hold.x; v[1] += hold.y; v[2] += hold.z; v[3] += hold.w;
            }
            if (SCATTER) {
                int gid = segs[r];
                float4 vv = (n < nrows) ? make_float4(v[0], v[1], v[2], v[3])
                                        : make_float4(0.f, 0.f, 0.f, 0.f);
                unsigned f = (tr == 0 || segs[r - 1] != gid) ? 1u : 0u;
#pragma unroll
                for (int s = 1; s < 32; s <<= 1) {
                    float ux = __shfl_up(vv.x, s, 32);
                    float uy = __shfl_up(vv.y, s, 32);
                    float uz = __shfl_up(vv.z, s, 32);
                    float uw = __shfl_up(vv.w, s, 32);
                    unsigned uf = __shfl_up(f, s, 32);
                    if (tr >= s) {
                        if (!f) { vv.x += ux; vv.y += uy; vv.z += uz; vv.w += uw; }
                        f |= uf;
                    }
                }
                bool tail = (tr == 31) || (segs[r + 1] != gid);
                if (tail && gid >= 0) {
                    float* bp = outp + 64 * gid + 4 * tc;
                    atomicAdd(bp + 0, vv.x); atomicAdd(bp + 1, vv.y);
                    atomicAdd(bp + 2, vv.z); atomicAdd(bp + 3, vv.w);
                }
            } else if (n < nrows) {
                *(float4*)&outp[64 * n + 4 * tc] = make_float4(v[0], v[1], v[2], v[3]);
            }
        }
    }
}

__global__ __launch_bounds__(256) void proj_kernel(
    const float* __restrict__ x, const float* __restrict__ w,
    const float* __restrict__ b, float* __restrict__ h, int n)
{
    int i = blockIdx.x * 256 + threadIdx.x;
    if (i >= n * 64) return;
    int node = i >> 6, j = i & 63;
    const float* xr = x + node * 14;
    float acc = b[j];
#pragma unroll
    for (int k = 0; k < 14; ++k) acc = fmaf(xr[k], w[k * 64 + j], acc);
    h[i] = acc;
}

__global__ __launch_bounds__(256) void head_kernel(
    const float* __restrict__ gsum,
    const float* __restrict__ w3, const float* __restrict__ b3,
    const float* __restrict__ w4, const float* __restrict__ b4,
    float* __restrict__ out, int g_count)
{
    int wid  = (blockIdx.x * 256 + threadIdx.x) >> 6;
    int lane = threadIdx.x & 63;
    if (wid >= g_count) return;
    float v = gsum[wid * 64 + lane];
    float t = b3[lane];
#pragma unroll
    for (int k = 0; k < 64; ++k) {
        float a = __shfl(v, k, 64);
        t = fmaf(a, w3[k * 64 + lane], t);
    }
    t = silu_f(t);
    float r = t * w4[lane];
#pragma unroll
    for (int off = 32; off; off >>= 1) r += __shfl_down(r, off, 64);
    if (lane == 0) out[wid] = r + b4[0];
}

extern "C" void kernel_launch(void* const* d_in, const int* in_sizes, int n_in,
                              void* d_out, int out_size, void* d_ws, size_t ws_size,
                              hipStream_t stream)
{
    const float* x      = (const float*)d_in[0];
    const int*   ei     = (const int*)d_in[2];
    const int*   batch  = (const int*)d_in[3];
    const float* proj_w = (const float*)d_in[4];
    const float* proj_b = (const float*)d_in[5];
    const float* ew1 = (const float*)d_in[6];
    const float* eb1 = (const float*)d_in[7];
    const float* ew2 = (const float*)d_in[8];
    const float* eb2 = (const float*)d_in[9];
    const float* nw1 = (const float*)d_in[10];
    const float* nb1 = (const float*)d_in[11];
    const float* nw2 = (const float*)d_in[12];
    const float* nb2 = (const float*)d_in[13];
    const float* l1w = (const float*)d_in[14]; const float* l1b = (const float*)d_in[15];
    const float* l2w = (const float*)d_in[16]; const float* l2b = (const float*)d_in[17];
    const float* l3w = (const float*)d_in[18]; const float* l3b = (const float*)d_in[19];
    const float* l4w = (const float*)d_in[20]; const float* l4b = (const float*)d_in[21];

    float* out  = (float*)d_out;
    float* h    = out + GG;                      // per_atom_out doubles as h

    float* agg  = (float*)d_ws;                  // [N,64]
    float* gsum = agg + (size_t)NN * 64;         // [G,64]
    int* deg    = (int*)(gsum + (size_t)GG * 64);
    int* rowptr = deg + NN;
    int* cursor = rowptr + NN + 1;
    int* srcsS  = cursor + NN;                   // [E]
    int* dstsS  = srcsS + EE;                    // [E]

    const size_t edge_lds = 150528;  // 3*16K + 2*32K + 34816 + 1024
    const size_t node_lds = (size_t)(8192 + 4096 + 128 + 128 * 132 + 128 * 68) * 4 + 128 * 4;
    const size_t ro_lds   = (size_t)(4096 + 4096 + 128 + 128 * 68 + 128 * 68) * 4 + 128 * 4;

    (void)hipFuncSetAttribute((const void*)edge_kernel,
                              hipFuncAttributeMaxDynamicSharedMemorySize, (int)edge_lds);
    (void)hipFuncSetAttribute((const void*)(rowmlp_kernel<128, false, true, false>),
                              hipFuncAttributeMaxDynamicSharedMemorySize, (int)node_lds);
    (void)hipFuncSetAttribute((const void*)(rowmlp_kernel<64, false, false, true>),
                              hipFuncAttributeMaxDynamicSharedMemorySize, (int)ro_lds);

    // --- CSR build (dst-sorted edge arrays), per call ---
    hipMemsetAsync(deg, 0, (size_t)NN * sizeof(int), stream);
    hipMemsetAsync(gsum, 0, (size_t)GG * 64 * sizeof(float), stream);
    hist_kernel<<<(EE + 255) / 256, 256, 0, stream>>>(ei, deg);
    scan_kernel<<<1, 1024, 0, stream>>>(deg, rowptr, cursor);
    scatter_kernel<<<(EE + 255) / 256, 256, 0, stream>>>(ei, cursor, srcsS, dstsS);

    proj_kernel<<<(NN * 64 + 255) / 256, 256, 0, stream>>>(x, proj_w, proj_b, h, NN);

    const int etiles = EE / 128;               // 6250
    const int ntiles = (NN + 127) / 128;       // 391
    for (int l = 0; l < LL; ++l) {
        hipMemsetAsync(agg, 0, (size_t)NN * 64 * sizeof(float), stream);
        edge_kernel<<<250, 512, edge_lds, stream>>>(
            h, srcsS, dstsS, ew1 + l * 8192, eb1 + l * 64, ew2 + l * 4096, eb2 + l * 64,
            agg, etiles);
        rowmlp_kernel<128, false, true, false><<<196, 512, node_lds, stream>>>(
            h, agg, nw1 + l * 8192, nb1 + l * 64, nw2 + l * 4096, nb2 + l * 64,
            nullptr, h, NN, ntiles);
    }
    rowmlp_kernel<64, false, false, true><<<196, 512, ro_lds, stream>>>(
        h, nullptr, l1w, l1b, l2w, l2b, batch, gsum, NN, ntiles);
    head_kernel<<<GG / 4, 256, 0, stream>>>(gsum, l3w, l3b, l4w, l4b, out, GG);
}

// Round 5
// 827.918 us; speedup vs baseline: 5.5668x; 1.1930x over previous
//
#include <hip/hip_runtime.h>

#define NN 50000
#define EE 800000
#define GG 512
#define LL 3

typedef short bf16x8 __attribute__((ext_vector_type(8)));
typedef float f32x4  __attribute__((ext_vector_type(4)));

__device__ __forceinline__ float silu_f(float x) {
    return x * __builtin_amdgcn_rcpf(1.0f + __expf(-x));
}
__device__ __forceinline__ unsigned short bf16_rne(float x) {
    unsigned u = __float_as_uint(x);
    u += 0x7fffu + ((u >> 16) & 1u);
    return (unsigned short)(u >> 16);
}
__device__ __forceinline__ f32x4 mfma16(bf16x8 a, bf16x8 b, f32x4 c) {
    return __builtin_amdgcn_mfma_f32_16x16x32_bf16(a, b, c, 0, 0, 0);
}

// ===========================================================================
// CSR build: histogram -> exclusive scan -> scatter into dst-sorted arrays
// ===========================================================================
__global__ __launch_bounds__(256) void hist_kernel(const int* __restrict__ ei,
                                                   int* __restrict__ deg) {
    int e = blockIdx.x * 256 + threadIdx.x;
    if (e < EE) atomicAdd(&deg[ei[EE + e]], 1);
}

__global__ __launch_bounds__(1024) void scan_kernel(const int* __restrict__ deg,
                                                    int* __restrict__ rowptr,
                                                    int* __restrict__ cursor) {
    __shared__ int wsum[16];
    __shared__ int sCarry;
    const int tid = threadIdx.x;
    const int lane = tid & 63, wid = tid >> 6;
    if (tid == 0) sCarry = 0;
    __syncthreads();
    for (int base = 0; base < NN; base += 1024) {
        int i = base + tid;
        int v = (i < NN) ? deg[i] : 0;
        int x = v;
#pragma unroll
        for (int s = 1; s < 64; s <<= 1) {
            int u = __shfl_up(x, s, 64);
            if (lane >= s) x += u;
        }
        if (lane == 63) wsum[wid] = x;
        __syncthreads();
        int woff = 0;
        for (int w = 0; w < wid; ++w) woff += wsum[w];
        int carry = sCarry;
        int excl = carry + woff + x - v;
        if (i < NN) { rowptr[i] = excl; cursor[i] = excl; }
        __syncthreads();
        if (tid == 1023) sCarry = carry + woff + x;
        __syncthreads();
    }
    if (tid == 0) rowptr[NN] = sCarry;
}

__global__ __launch_bounds__(256) void scatter_kernel(const int* __restrict__ ei,
                                                      int* __restrict__ cursor,
                                                      int* __restrict__ srcsS,
                                                      int* __restrict__ dstsS) {
    int e = blockIdx.x * 256 + threadIdx.x;
    if (e < EE) {
        int d = ei[EE + e];
        int pos = atomicAdd(&cursor[d], 1);
        srcsS[pos] = ei[e];
        dstsS[pos] = d;
    }
}

// ===========================================================================
// pk_kernel: Pt = h @ W1[0:64], Pb = h @ W1[64:128]  (fp32, exact stage-1)
// 512 thr, 128-row tiles, 4x4 micro-tile per thread, two output passes.
// ===========================================================================
__global__ __launch_bounds__(512, 4) void pk_kernel(
    const float* __restrict__ h, const float* __restrict__ w1g,
    float* __restrict__ Pt, float* __restrict__ Pb, int ntiles)
{
    extern __shared__ float lds[];
    float* ws = lds;            // [128][64] f32 = 32 KB
    float* hs = ws + 8192;      // [128][68] f32 = 34.8 KB
    const int tid = threadIdx.x;
    const int tr  = tid & 31;
    const int tc  = tid >> 5;

    for (int i = tid; i < 2048; i += 512)
        *(float4*)&ws[4 * i] = *(const float4*)&w1g[4 * i];

    for (int tile = blockIdx.x; tile < ntiles; tile += gridDim.x) {
        const int base = tile * 128;
        __syncthreads();
#pragma unroll
        for (int rep = 0; rep < 4; ++rep) {
            int idx = rep * 512 + tid;
            int r = idx >> 4, q = idx & 15;
            int n = base + r;
            float4 v = make_float4(0.f, 0.f, 0.f, 0.f);
            if (n < NN) v = *(const float4*)(h + 64 * n + 4 * q);
            *(float4*)&hs[r * 68 + 4 * q] = v;
        }
        __syncthreads();
#pragma unroll
        for (int p = 0; p < 2; ++p) {
            float acc[4][4];
#pragma unroll
            for (int jj = 0; jj < 4; ++jj)
#pragma unroll
                for (int ii = 0; ii < 4; ++ii) acc[jj][ii] = 0.f;
#pragma unroll 4
            for (int k16 = 0; k16 < 16; ++k16) {
                float4 bv0 = *(const float4*)&ws[(p * 64 + 4 * k16 + 0) * 64 + 4 * tc];
                float4 bv1 = *(const float4*)&ws[(p * 64 + 4 * k16 + 1) * 64 + 4 * tc];
                float4 bv2 = *(const float4*)&ws[(p * 64 + 4 * k16 + 2) * 64 + 4 * tc];
                float4 bv3 = *(const float4*)&ws[(p * 64 + 4 * k16 + 3) * 64 + 4 * tc];
#pragma unroll
                for (int jj = 0; jj < 4; ++jj) {
                    float4 av = *(const float4*)&hs[(tr + 32 * jj) * 68 + 4 * k16];
                    acc[jj][0] = fmaf(av.x, bv0.x, fmaf(av.y, bv1.x, fmaf(av.z, bv2.x, fmaf(av.w, bv3.x, acc[jj][0]))));
                    acc[jj][1] = fmaf(av.x, bv0.y, fmaf(av.y, bv1.y, fmaf(av.z, bv2.y, fmaf(av.w, bv3.y, acc[jj][1]))));
                    acc[jj][2] = fmaf(av.x, bv0.z, fmaf(av.y, bv1.z, fmaf(av.z, bv2.z, fmaf(av.w, bv3.z, acc[jj][2]))));
                    acc[jj][3] = fmaf(av.x, bv0.w, fmaf(av.y, bv1.w, fmaf(av.z, bv2.w, fmaf(av.w, bv3.w, acc[jj][3]))));
                }
            }
            float* outp = p ? Pb : Pt;
#pragma unroll
            for (int jj = 0; jj < 4; ++jj) {
                int n = base + tr + 32 * jj;
                if (n < NN)
                    *(float4*)(outp + 64 * n + 4 * tc) =
                        make_float4(acc[jj][0], acc[jj][1], acc[jj][2], acc[jj][3]);
            }
        }
    }
}

// ===========================================================================
// Edge kernel (stage-1-free): per 128-edge dst-sorted tile
//   m1 = silu(Pt[dst] + Pb[src] + b1)        (fp32 math, bf16 store)
//   m2 = silu(m1 @ W2 + b2)                  (MFMA, bf16 inputs)
//   segmented reduce over sorted dst runs -> tail atomics into agg
// LDS 59 KB -> 2 blocks/CU (16 waves). 8 waves, wave w: rows 32(w>>1), cols 32(w&1).
// ===========================================================================
__global__ __launch_bounds__(512, 4) void edge_kernel(
    const float* __restrict__ Pt, const float* __restrict__ Pb,
    const int* __restrict__ srcsS, const int* __restrict__ dstsS,
    const float* __restrict__ b1g,
    const float* __restrict__ w2g, const float* __restrict__ b2g,
    float* __restrict__ agg, int ntiles)
{
    extern __shared__ __align__(16) char smem[];
    char*  wt2s  = smem;                          // [64c][128B] swz  8192
    char*  m1s   = wt2s + 8192;                   // [128r][128B] swz 16384
    float* m2f   = (float*)(m1s + 16384);         // [128][68] f32    34816
    float* b1s   = (float*)((char*)m2f + 34816);  // 64 f32
    float* b2s   = b1s + 64;                      // 64 f32
    int*   dstsL = (int*)(b2s + 64);              // 128 int

    const int tid = threadIdx.x;
    const int l   = tid & 63;
    const int w   = tid >> 6;
    const int mi  = w >> 1;
    const int ni  = w & 1;
    const int l15 = l & 15;
    const int l4  = l >> 4;

    // stage W2^T (col-major rows) bf16, XOR swizzle ((c&7)<<4) within 128B rows
    {
        int c = tid >> 3, kc = tid & 7;
        const float* wp = w2g + (kc * 8) * 64 + c;
        bf16x8 bv;
#pragma unroll
        for (int j = 0; j < 8; ++j) bv[j] = (short)bf16_rne(wp[j * 64]);
        *(bf16x8*)(wt2s + c * 128 + ((kc * 16) ^ ((c & 7) << 4))) = bv;
    }
    if (tid < 64) { b1s[tid] = b1g[tid]; b2s[tid] = b2g[tid]; }

    for (int tile = blockIdx.x; tile < ntiles; tile += gridDim.x) {
        const int ebase = tile * 128;
        __syncthreads();                          // B0: prev reduce done / staging visible
        if (tid < 128) dstsL[tid] = dstsS[ebase + tid];
        // fused gather: m1 = silu(Pt[dst]+Pb[src]+b1) -> bf16 swizzled LDS
#pragma unroll
        for (int rep = 0; rep < 4; ++rep) {
            int idx = rep * 512 + tid;            // 2048 float4-chunks
            int e = idx >> 4, q = idx & 15;
            int dn = dstsS[ebase + e], sn = srcsS[ebase + e];
            float4 a  = *(const float4*)(Pt + 64 * dn + 4 * q);
            float4 b  = *(const float4*)(Pb + 64 * sn + 4 * q);
            float4 bb = *(const float4*)(b1s + 4 * q);
            float v0 = silu_f(a.x + b.x + bb.x);
            float v1 = silu_f(a.y + b.y + bb.y);
            float v2 = silu_f(a.z + b.z + bb.z);
            float v3 = silu_f(a.w + b.w + bb.w);
            uint2 pk;
            pk.x = ((unsigned)bf16_rne(v1) << 16) | bf16_rne(v0);
            pk.y = ((unsigned)bf16_rne(v3) << 16) | bf16_rne(v2);
            *(uint2*)(m1s + e * 128 + ((q * 8) ^ ((e & 7) << 4))) = pk;
        }
        __syncthreads();                          // B1: m1s + dstsL ready
        // stage 2: m1[128x64] @ W2[64x64]
        f32x4 acc2[2][2];
#pragma unroll
        for (int m = 0; m < 2; ++m)
#pragma unroll
            for (int n = 0; n < 2; ++n) {
                float b = b2s[32 * ni + 16 * n + l15];
                acc2[m][n] = (f32x4){b, b, b, b};
            }
        const int sw = (l15 & 7) << 4;
#pragma unroll
        for (int ks = 0; ks < 2; ++ks) {
            int kb = ks * 64 + l4 * 16;
            bf16x8 af[2], bfr[2];
#pragma unroll
            for (int m = 0; m < 2; ++m)
                af[m] = *(const bf16x8*)(m1s + (32 * mi + 16 * m + l15) * 128 + (kb ^ sw));
#pragma unroll
            for (int n = 0; n < 2; ++n)
                bfr[n] = *(const bf16x8*)(wt2s + (32 * ni + 16 * n + l15) * 128 + (kb ^ sw));
#pragma unroll
            for (int m = 0; m < 2; ++m)
#pragma unroll
                for (int n = 0; n < 2; ++n)
                    acc2[m][n] = mfma16(af[m], bfr[n], acc2[m][n]);
        }
        // m2 = silu -> f32 LDS (C/D: col=lane&15, row=(lane>>4)*4+reg)
#pragma unroll
        for (int m = 0; m < 2; ++m)
#pragma unroll
            for (int n = 0; n < 2; ++n)
#pragma unroll
                for (int r = 0; r < 4; ++r) {
                    int row = 32 * mi + 16 * m + l4 * 4 + r;
                    m2f[row * 68 + 32 * ni + 16 * n + l15] = silu_f(acc2[m][n][r]);
                }
        __syncthreads();                          // B2: m2f complete
        // segmented reduce over sorted dsts, flush tails only
        const int tr = tid & 31, tc = tid >> 5;
#pragma unroll
        for (int jj = 0; jj < 4; ++jj) {
            int r = 32 * jj + tr;
            int d = dstsL[r];
            float4 v = *(const float4*)&m2f[r * 68 + 4 * tc];
            unsigned f = (tr == 0 || dstsL[r - 1] != d) ? 1u : 0u;
#pragma unroll
            for (int s = 1; s < 32; s <<= 1) {
                float ux = __shfl_up(v.x, s, 32);
                float uy = __shfl_up(v.y, s, 32);
                float uz = __shfl_up(v.z, s, 32);
                float uw = __shfl_up(v.w, s, 32);
                unsigned uf = __shfl_up(f, s, 32);
                if (tr >= s) {
                    if (!f) { v.x += ux; v.y += uy; v.z += uz; v.w += uw; }
                    f |= uf;
                }
            }
            bool tail = (tr == 31) || (dstsL[r + 1] != d);
            if (tail) {
                float* bp = agg + 64 * d + 4 * tc;
                atomicAdd(bp + 0, v.x); atomicAdd(bp + 1, v.y);
                atomicAdd(bp + 2, v.z); atomicAdd(bp + 3, v.w);
            }
        }
    }
}

// ===========================================================================
// Row-MLP kernel (node update / readout) — unchanged (fp32, proven).
// ===========================================================================
template <int K1, bool SILU2, bool RESID, bool SCATTER>
__global__ __launch_bounds__(512, 1) void rowmlp_kernel(
    const float* __restrict__ A, const float* __restrict__ A2,
    const float* __restrict__ w1g, const float* __restrict__ b1g,
    const float* __restrict__ w2g, const float* __restrict__ b2g,
    const int* __restrict__ seg, float* __restrict__ outp,
    int nrows, int ntiles)
{
    constexpr int CST = K1 + 4;
    constexpr int QN  = K1 / 4;
    constexpr int QSH = (K1 == 128) ? 5 : 4;
    constexpr int REPS = QN / 4;

    extern __shared__ float lds[];
    float* ws1  = lds;
    float* ws2  = ws1 + K1 * 64;
    float* wb1  = ws2 + 4096;
    float* wb2  = wb1 + 64;
    float* cats = wb2 + 64;
    float* m1s  = cats + 128 * CST;
    int*   segs = (int*)(m1s + 128 * 68);

    const int tid = threadIdx.x;
    const int tr  = tid & 31;
    const int tc  = tid >> 5;

    for (int i = tid; i < K1 * 16; i += 512)
        *(float4*)&ws1[4 * i] = *(const float4*)&w1g[4 * i];
    for (int i = tid; i < 1024; i += 512)
        *(float4*)&ws2[4 * i] = *(const float4*)&w2g[4 * i];
    if (tid < 64) { wb1[tid] = b1g[tid]; wb2[tid] = b2g[tid]; }

    for (int tile = blockIdx.x; tile < ntiles; tile += gridDim.x) {
        const int base = tile * 128;
        __syncthreads();
        if (SCATTER) {
            if (tid < 128) segs[tid] = (base + tid < nrows) ? seg[base + tid] : -1;
        }
#pragma unroll
        for (int rep = 0; rep < REPS; ++rep) {
            int idx = rep * 512 + tid;
            int r = idx >> QSH, q = idx & (QN - 1);
            int n = base + r;
            float4 v = make_float4(0.f, 0.f, 0.f, 0.f);
            if (n < nrows) {
                if constexpr (K1 == 128)
                    v = (q < 16) ? *(const float4*)(A + 64 * n + 4 * q)
                                 : *(const float4*)(A2 + 64 * n + 4 * (q - 16));
                else
                    v = *(const float4*)(A + 64 * n + 4 * q);
            }
            *(float4*)&cats[r * CST + 4 * q] = v;
        }
        __syncthreads();
        float acc[4][4];
#pragma unroll
        for (int jj = 0; jj < 4; ++jj)
#pragma unroll
            for (int ii = 0; ii < 4; ++ii) acc[jj][ii] = wb1[4 * tc + ii];
#pragma unroll 4
        for (int k16 = 0; k16 < K1 / 4; ++k16) {
            float4 bv0 = *(const float4*)&ws1[(4 * k16 + 0) * 64 + 4 * tc];
            float4 bv1 = *(const float4*)&ws1[(4 * k16 + 1) * 64 + 4 * tc];
            float4 bv2 = *(const float4*)&ws1[(4 * k16 + 2) * 64 + 4 * tc];
            float4 bv3 = *(const float4*)&ws1[(4 * k16 + 3) * 64 + 4 * tc];
#pragma unroll
            for (int jj = 0; jj < 4; ++jj) {
                float4 av = *(const float4*)&cats[(tr + 32 * jj) * CST + 4 * k16];
                acc[jj][0] = fmaf(av.x, bv0.x, fmaf(av.y, bv1.x, fmaf(av.z, bv2.x, fmaf(av.w, bv3.x, acc[jj][0]))));
                acc[jj][1] = fmaf(av.x, bv0.y, fmaf(av.y, bv1.y, fmaf(av.z, bv2.y, fmaf(av.w, bv3.y, acc[jj][1]))));
                acc[jj][2] = fmaf(av.x, bv0.z, fmaf(av.y, bv1.z, fmaf(av.z, bv2.z, fmaf(av.w, bv3.z, acc[jj][2]))));
                acc[jj][3] = fmaf(av.x, bv0.w, fmaf(av.y, bv1.w, fmaf(av.z, bv2.w, fmaf(av.w, bv3.w, acc[jj][3]))));
            }
        }
#pragma unroll
        for (int jj = 0; jj < 4; ++jj) {
            float4 v;
            v.x = silu_f(acc[jj][0]); v.y = silu_f(acc[jj][1]);
            v.z = silu_f(acc[jj][2]); v.w = silu_f(acc[jj][3]);
            *(float4*)&m1s[(tr + 32 * jj) * 68 + 4 * tc] = v;
        }
        __syncthreads();
        float acc2[4][4];
#pragma unroll
        for (int jj = 0; jj < 4; ++jj)
#pragma unroll
            for (int ii = 0; ii < 4; ++ii) acc2[jj][ii] = wb2[4 * tc + ii];
#pragma unroll 4
        for (int k16 = 0; k16 < 16; ++k16) {
            float4 bv0 = *(const float4*)&ws2[(4 * k16 + 0) * 64 + 4 * tc];
            float4 bv1 = *(const float4*)&ws2[(4 * k16 + 1) * 64 + 4 * tc];
            float4 bv2 = *(const float4*)&ws2[(4 * k16 + 2) * 64 + 4 * tc];
            float4 bv3 = *(const float4*)&ws2[(4 * k16 + 3) * 64 + 4 * tc];
#pragma unroll
            for (int jj = 0; jj < 4; ++jj) {
                float4 av = *(const float4*)&m1s[(tr + 32 * jj) * 68 + 4 * k16];
                acc2[jj][0] = fmaf(av.x, bv0.x, fmaf(av.y, bv1.x, fmaf(av.z, bv2.x, fmaf(av.w, bv3.x, acc2[jj][0]))));
                acc2[jj][1] = fmaf(av.x, bv0.y, fmaf(av.y, bv1.y, fmaf(av.z, bv2.y, fmaf(av.w, bv3.y, acc2[jj][1]))));
                acc2[jj][2] = fmaf(av.x, bv0.z, fmaf(av.y, bv1.z, fmaf(av.z, bv2.z, fmaf(av.w, bv3.z, acc2[jj][2]))));
                acc2[jj][3] = fmaf(av.x, bv0.w, fmaf(av.y, bv1.w, fmaf(av.z, bv2.w, fmaf(av.w, bv3.w, acc2[jj][3]))));
            }
        }
#pragma unroll
        for (int jj = 0; jj < 4; ++jj) {
            int r = tr + 32 * jj;
            int n = base + r;
            float v[4];
#pragma unroll
            for (int ii = 0; ii < 4; ++ii)
                v[ii] = SILU2 ? silu_f(acc2[jj][ii]) : acc2[jj][ii];
            if (RESID) {
                float4 hold = *(const float4*)&cats[r * CST + 4 * tc];
                v[0] += hold.x; v[1] += hold.y; v[2] += hold.z; v[3] += hold.w;
            }
            if (SCATTER) {
                int gid = segs[r];
                float4 vv = (n < nrows) ? make_float4(v[0], v[1], v[2], v[3])
                                        : make_float4(0.f, 0.f, 0.f, 0.f);
                unsigned f = (tr == 0 || segs[r - 1] != gid) ? 1u : 0u;
#pragma unroll
                for (int s = 1; s < 32; s <<= 1) {
                    float ux = __shfl_up(vv.x, s, 32);
                    float uy = __shfl_up(vv.y, s, 32);
                    float uz = __shfl_up(vv.z, s, 32);
                    float uw = __shfl_up(vv.w, s, 32);
                    unsigned uf = __shfl_up(f, s, 32);
                    if (tr >= s) {
                        if (!f) { vv.x += ux; vv.y += uy; vv.z += uz; vv.w += uw; }
                        f |= uf;
                    }
                }
                bool tail = (tr == 31) || (segs[r + 1] != gid);
                if (tail && gid >= 0) {
                    float* bp = outp + 64 * gid + 4 * tc;
                    atomicAdd(bp + 0, vv.x); atomicAdd(bp + 1, vv.y);
                    atomicAdd(bp + 2, vv.z); atomicAdd(bp + 3, vv.w);
                }
            } else if (n < nrows) {
                *(float4*)&outp[64 * n + 4 * tc] = make_float4(v[0], v[1], v[2], v[3]);
            }
        }
    }
}

__global__ __launch_bounds__(256) void proj_kernel(
    const float* __restrict__ x, const float* __restrict__ w,
    const float* __restrict__ b, float* __restrict__ h, int n)
{
    int i = blockIdx.x * 256 + threadIdx.x;
    if (i >= n * 64) return;
    int node = i >> 6, j = i & 63;
    const float* xr = x + node * 14;
    float acc = b[j];
#pragma unroll
    for (int k = 0; k < 14; ++k) acc = fmaf(xr[k], w[k * 64 + j], acc);
    h[i] = acc;
}

__global__ __launch_bounds__(256) void head_kernel(
    const float* __restrict__ gsum,
    const float* __restrict__ w3, const float* __restrict__ b3,
    const float* __restrict__ w4, const float* __restrict__ b4,
    float* __restrict__ out, int g_count)
{
    int wid  = (blockIdx.x * 256 + threadIdx.x) >> 6;
    int lane = threadIdx.x & 63;
    if (wid >= g_count) return;
    float v = gsum[wid * 64 + lane];
    float t = b3[lane];
#pragma unroll
    for (int k = 0; k < 64; ++k) {
        float a = __shfl(v, k, 64);
        t = fmaf(a, w3[k * 64 + lane], t);
    }
    t = silu_f(t);
    float r = t * w4[lane];
#pragma unroll
    for (int off = 32; off; off >>= 1) r += __shfl_down(r, off, 64);
    if (lane == 0) out[wid] = r + b4[0];
}

extern "C" void kernel_launch(void* const* d_in, const int* in_sizes, int n_in,
                              void* d_out, int out_size, void* d_ws, size_t ws_size,
                              hipStream_t stream)
{
    const float* x      = (const float*)d_in[0];
    const int*   ei     = (const int*)d_in[2];
    const int*   batch  = (const int*)d_in[3];
    const float* proj_w = (const float*)d_in[4];
    const float* proj_b = (const float*)d_in[5];
    const float* ew1 = (const float*)d_in[6];
    const float* eb1 = (const float*)d_in[7];
    const float* ew2 = (const float*)d_in[8];
    const float* eb2 = (const float*)d_in[9];
    const float* nw1 = (const float*)d_in[10];
    const float* nb1 = (const float*)d_in[11];
    const float* nw2 = (const float*)d_in[12];
    const float* nb2 = (const float*)d_in[13];
    const float* l1w = (const float*)d_in[14]; const float* l1b = (const float*)d_in[15];
    const float* l2w = (const float*)d_in[16]; const float* l2b = (const float*)d_in[17];
    const float* l3w = (const float*)d_in[18]; const float* l3b = (const float*)d_in[19];
    const float* l4w = (const float*)d_in[20]; const float* l4b = (const float*)d_in[21];

    float* out  = (float*)d_out;
    float* h    = out + GG;                      // per_atom_out doubles as h

    float* agg  = (float*)d_ws;                  // [N,64]
    float* gsum = agg + (size_t)NN * 64;         // [G,64]
    float* Pt   = gsum + (size_t)GG * 64;        // [N,64]
    float* Pb   = Pt + (size_t)NN * 64;          // [N,64]
    int* deg    = (int*)(Pb + (size_t)NN * 64);
    int* rowptr = deg + NN;
    int* cursor = rowptr + NN + 1;
    int* srcsS  = cursor + NN;                   // [E]
    int* dstsS  = srcsS + EE;                    // [E]

    const size_t edge_lds = 8192 + 16384 + 34816 + 256 + 256 + 512;   // 60416
    const size_t pk_lds   = (size_t)(8192 + 8704) * 4;                // 67584
    const size_t node_lds = (size_t)(8192 + 4096 + 128 + 128 * 132 + 128 * 68) * 4 + 128 * 4;
    const size_t ro_lds   = (size_t)(4096 + 4096 + 128 + 128 * 68 + 128 * 68) * 4 + 128 * 4;

    (void)hipFuncSetAttribute((const void*)edge_kernel,
                              hipFuncAttributeMaxDynamicSharedMemorySize, (int)edge_lds);
    (void)hipFuncSetAttribute((const void*)pk_kernel,
                              hipFuncAttributeMaxDynamicSharedMemorySize, (int)pk_lds);
    (void)hipFuncSetAttribute((const void*)(rowmlp_kernel<128, false, true, false>),
                              hipFuncAttributeMaxDynamicSharedMemorySize, (int)node_lds);
    (void)hipFuncSetAttribute((const void*)(rowmlp_kernel<64, false, false, true>),
                              hipFuncAttributeMaxDynamicSharedMemorySize, (int)ro_lds);

    // --- CSR build (dst-sorted edge arrays) ---
    hipMemsetAsync(deg, 0, (size_t)NN * sizeof(int), stream);
    hipMemsetAsync(gsum, 0, (size_t)GG * 64 * sizeof(float), stream);
    hist_kernel<<<(EE + 255) / 256, 256, 0, stream>>>(ei, deg);
    scan_kernel<<<1, 1024, 0, stream>>>(deg, rowptr, cursor);
    scatter_kernel<<<(EE + 255) / 256, 256, 0, stream>>>(ei, cursor, srcsS, dstsS);

    proj_kernel<<<(NN * 64 + 255) / 256, 256, 0, stream>>>(x, proj_w, proj_b, h, NN);

    const int etiles = EE / 128;               // 6250
    const int ntiles = (NN + 127) / 128;       // 391
    for (int l = 0; l < LL; ++l) {
        pk_kernel<<<ntiles, 512, pk_lds, stream>>>(h, ew1 + l * 8192, Pt, Pb, ntiles);
        hipMemsetAsync(agg, 0, (size_t)NN * 64 * sizeof(float), stream);
        edge_kernel<<<512, 512, edge_lds, stream>>>(
            Pt, Pb, srcsS, dstsS, eb1 + l * 64, ew2 + l * 4096, eb2 + l * 64,
            agg, etiles);
        rowmlp_kernel<128, false, true, false><<<196, 512, node_lds, stream>>>(
            h, agg, nw1 + l * 8192, nb1 + l * 64, nw2 + l * 4096, nb2 + l * 64,
            nullptr, h, NN, ntiles);
    }
    rowmlp_kernel<64, false, false, true><<<196, 512, ro_lds, stream>>>(
        h, nullptr, l1w, l1b, l2w, l2b, batch, gsum, NN, ntiles);
    head_kernel<<<GG / 4, 256, 0, stream>>>(gsum, l3w, l3b, l4w, l4b, out, GG);
}

// Round 6
// 824.164 us; speedup vs baseline: 5.5922x; 1.0046x over previous
//
#include <hip/hip_runtime.h>

#define NN 50000
#define EE 800000
#define GG 512
#define LL 3

typedef short bf16x8 __attribute__((ext_vector_type(8)));
typedef float f32x4  __attribute__((ext_vector_type(4)));

__device__ __forceinline__ float silu_f(float x) {
    return x * __builtin_amdgcn_rcpf(1.0f + __expf(-x));
}
__device__ __forceinline__ unsigned short bf16_rne(float x) {
    unsigned u = __float_as_uint(x);
    u += 0x7fffu + ((u >> 16) & 1u);
    return (unsigned short)(u >> 16);
}
__device__ __forceinline__ float bflo(unsigned u) { return __uint_as_float(u << 16); }
__device__ __forceinline__ float bfhi(unsigned u) { return __uint_as_float(u & 0xffff0000u); }
__device__ __forceinline__ f32x4 mfma16(bf16x8 a, bf16x8 b, f32x4 c) {
    return __builtin_amdgcn_mfma_f32_16x16x32_bf16(a, b, c, 0, 0, 0);
}

// ===========================================================================
// CSR build: histogram -> exclusive scan -> scatter into dst-sorted arrays
// ===========================================================================
__global__ __launch_bounds__(256) void hist_kernel(const int* __restrict__ ei,
                                                   int* __restrict__ deg) {
    int e = blockIdx.x * 256 + threadIdx.x;
    if (e < EE) atomicAdd(&deg[ei[EE + e]], 1);
}

__global__ __launch_bounds__(1024) void scan_kernel(const int* __restrict__ deg,
                                                    int* __restrict__ rowptr,
                                                    int* __restrict__ cursor) {
    __shared__ int wsum[16];
    __shared__ int sCarry;
    const int tid = threadIdx.x;
    const int lane = tid & 63, wid = tid >> 6;
    if (tid == 0) sCarry = 0;
    __syncthreads();
    for (int base = 0; base < NN; base += 1024) {
        int i = base + tid;
        int v = (i < NN) ? deg[i] : 0;
        int x = v;
#pragma unroll
        for (int s = 1; s < 64; s <<= 1) {
            int u = __shfl_up(x, s, 64);
            if (lane >= s) x += u;
        }
        if (lane == 63) wsum[wid] = x;
        __syncthreads();
        int woff = 0;
        for (int w = 0; w < wid; ++w) woff += wsum[w];
        int carry = sCarry;
        int excl = carry + woff + x - v;
        if (i < NN) { rowptr[i] = excl; cursor[i] = excl; }
        __syncthreads();
        if (tid == 1023) sCarry = carry + woff + x;
        __syncthreads();
    }
    if (tid == 0) rowptr[NN] = sCarry;
}

__global__ __launch_bounds__(256) void scatter_kernel(const int* __restrict__ ei,
                                                      int* __restrict__ cursor,
                                                      int* __restrict__ srcsS,
                                                      int* __restrict__ dstsS) {
    int e = blockIdx.x * 256 + threadIdx.x;
    if (e < EE) {
        int d = ei[EE + e];
        int pos = atomicAdd(&cursor[d], 1);
        srcsS[pos] = ei[e];
        dstsS[pos] = d;
    }
}

// ===========================================================================
// pk_kernel: Pt = h @ W1[0:64] (f32), Pb = h @ W1[64:128] (bf16 packed)
// ===========================================================================
__global__ __launch_bounds__(512, 4) void pk_kernel(
    const float* __restrict__ h, const float* __restrict__ w1g,
    float* __restrict__ Pt, unsigned short* __restrict__ Pbu, int ntiles)
{
    extern __shared__ float lds[];
    float* ws = lds;            // [128][64] f32 = 32 KB
    float* hs = ws + 8192;      // [128][68] f32 = 34.8 KB
    const int tid = threadIdx.x;
    const int tr  = tid & 31;
    const int tc  = tid >> 5;

    for (int i = tid; i < 2048; i += 512)
        *(float4*)&ws[4 * i] = *(const float4*)&w1g[4 * i];

    for (int tile = blockIdx.x; tile < ntiles; tile += gridDim.x) {
        const int base = tile * 128;
        __syncthreads();
#pragma unroll
        for (int rep = 0; rep < 4; ++rep) {
            int idx = rep * 512 + tid;
            int r = idx >> 4, q = idx & 15;
            int n = base + r;
            float4 v = make_float4(0.f, 0.f, 0.f, 0.f);
            if (n < NN) v = *(const float4*)(h + 64 * n + 4 * q);
            *(float4*)&hs[r * 68 + 4 * q] = v;
        }
        __syncthreads();
#pragma unroll
        for (int p = 0; p < 2; ++p) {
            float acc[4][4];
#pragma unroll
            for (int jj = 0; jj < 4; ++jj)
#pragma unroll
                for (int ii = 0; ii < 4; ++ii) acc[jj][ii] = 0.f;
#pragma unroll 4
            for (int k16 = 0; k16 < 16; ++k16) {
                float4 bv0 = *(const float4*)&ws[(p * 64 + 4 * k16 + 0) * 64 + 4 * tc];
                float4 bv1 = *(const float4*)&ws[(p * 64 + 4 * k16 + 1) * 64 + 4 * tc];
                float4 bv2 = *(const float4*)&ws[(p * 64 + 4 * k16 + 2) * 64 + 4 * tc];
                float4 bv3 = *(const float4*)&ws[(p * 64 + 4 * k16 + 3) * 64 + 4 * tc];
#pragma unroll
                for (int jj = 0; jj < 4; ++jj) {
                    float4 av = *(const float4*)&hs[(tr + 32 * jj) * 68 + 4 * k16];
                    acc[jj][0] = fmaf(av.x, bv0.x, fmaf(av.y, bv1.x, fmaf(av.z, bv2.x, fmaf(av.w, bv3.x, acc[jj][0]))));
                    acc[jj][1] = fmaf(av.x, bv0.y, fmaf(av.y, bv1.y, fmaf(av.z, bv2.y, fmaf(av.w, bv3.y, acc[jj][1]))));
                    acc[jj][2] = fmaf(av.x, bv0.z, fmaf(av.y, bv1.z, fmaf(av.z, bv2.z, fmaf(av.w, bv3.z, acc[jj][2]))));
                    acc[jj][3] = fmaf(av.x, bv0.w, fmaf(av.y, bv1.w, fmaf(av.z, bv2.w, fmaf(av.w, bv3.w, acc[jj][3]))));
                }
            }
#pragma unroll
            for (int jj = 0; jj < 4; ++jj) {
                int n = base + tr + 32 * jj;
                if (n < NN) {
                    if (p == 0) {
                        *(float4*)(Pt + (size_t)64 * n + 4 * tc) =
                            make_float4(acc[jj][0], acc[jj][1], acc[jj][2], acc[jj][3]);
                    } else {
                        uint2 o;
                        o.x = ((unsigned)bf16_rne(acc[jj][1]) << 16) | bf16_rne(acc[jj][0]);
                        o.y = ((unsigned)bf16_rne(acc[jj][3]) << 16) | bf16_rne(acc[jj][2]);
                        *(uint2*)(Pbu + (size_t)64 * n + 4 * tc) = o;
                    }
                }
            }
        }
    }
}

// ===========================================================================
// Edge kernel with software prefetch: per 128-edge dst-sorted tile
//   m1 = silu(Pt[dst] + Pb[src] + b1)  (Pt f32, Pb bf16; bf16 store to LDS)
//   m2 = silu(m1 @ W2 + b2)            (MFMA)
//   segmented reduce over sorted dst runs -> tail atomics into agg
// Loop: consume(regs)->m1s | B1 | PREFETCH(t+1) | MFMA+m2f | B2 | reduce.
// LDS 60928 B -> 2 blocks/CU; dstsL double-buffered; 2 barriers/tile.
// ===========================================================================
__global__ __launch_bounds__(512, 4) void edge_kernel(
    const float* __restrict__ Pt, const unsigned short* __restrict__ Pbu,
    const int* __restrict__ srcsS, const int* __restrict__ dstsS,
    const float* __restrict__ b1g,
    const float* __restrict__ w2g, const float* __restrict__ b2g,
    float* __restrict__ agg, int ntiles)
{
    extern __shared__ __align__(16) char smem[];
    char*  wt2s  = smem;                          // [64c][128B] swz   8192
    char*  m1s   = wt2s + 8192;                   // [128r][128B] swz 16384
    float* m2f   = (float*)(m1s + 16384);         // [128][68] f32    34816
    float* b1s   = (float*)((char*)m2f + 34816);  // 64 f32
    float* b2s   = b1s + 64;                      // 64 f32
    int*   dstsL = (int*)(b2s + 64);              // 2 x 128 int

    const int tid = threadIdx.x;
    const int l   = tid & 63;
    const int w   = tid >> 6;
    const int mi  = w >> 1;
    const int ni  = w & 1;
    const int l15 = l & 15;
    const int l4  = l >> 4;

    // stage W2^T bf16, XOR swizzle ((c&7)<<4) within 128B rows
    {
        int c = tid >> 3, kc = tid & 7;
        const float* wp = w2g + (kc * 8) * 64 + c;
        bf16x8 bv;
#pragma unroll
        for (int j = 0; j < 8; ++j) bv[j] = (short)bf16_rne(wp[j * 64]);
        *(bf16x8*)(wt2s + c * 128 + ((kc * 16) ^ ((c & 7) << 4))) = bv;
    }
    if (tid < 64) { b1s[tid] = b1g[tid]; b2s[tid] = b2g[tid]; }

    float4 pf_a0[2], pf_a1[2];
    uint4  pf_pb[2];
    int    pf_d = 0;
    auto PRE = [&](int tt) {
        int eb = tt * 128;
#pragma unroll
        for (int it = 0; it < 2; ++it) {
            int itm = it * 512 + tid;
            int e = itm >> 3, g = itm & 7;
            int dn = dstsS[eb + e], sn = srcsS[eb + e];
            const float* pt = Pt + (size_t)64 * dn + 8 * g;
            pf_a0[it] = *(const float4*)pt;
            pf_a1[it] = *(const float4*)(pt + 4);
            pf_pb[it] = *(const uint4*)(Pbu + (size_t)64 * sn + 8 * g);
        }
        pf_d = (tid < 128) ? dstsS[eb + tid] : 0;
    };

    int tile = blockIdx.x;
    int buf  = 0;
    if (tile < ntiles) PRE(tile);
    __syncthreads();                              // staging (wt2s,b1s,b2s) visible

    for (; tile < ntiles; tile += gridDim.x) {
        if (tid < 128) dstsL[buf * 128 + tid] = pf_d;
        // ---- consume prefetched regs -> m1 bf16 swizzled LDS ----
#pragma unroll
        for (int it = 0; it < 2; ++it) {
            int itm = it * 512 + tid;
            int e = itm >> 3, g = itm & 7;
            float4 b0  = *(const float4*)(b1s + 8 * g);
            float4 b1v = *(const float4*)(b1s + 8 * g + 4);
            float v0 = silu_f(pf_a0[it].x + bflo(pf_pb[it].x) + b0.x);
            float v1 = silu_f(pf_a0[it].y + bfhi(pf_pb[it].x) + b0.y);
            float v2 = silu_f(pf_a0[it].z + bflo(pf_pb[it].y) + b0.z);
            float v3 = silu_f(pf_a0[it].w + bfhi(pf_pb[it].y) + b0.w);
            float v4 = silu_f(pf_a1[it].x + bflo(pf_pb[it].z) + b1v.x);
            float v5 = silu_f(pf_a1[it].y + bfhi(pf_pb[it].z) + b1v.y);
            float v6 = silu_f(pf_a1[it].z + bflo(pf_pb[it].w) + b1v.z);
            float v7 = silu_f(pf_a1[it].w + bfhi(pf_pb[it].w) + b1v.w);
            uint4 o;
            o.x = ((unsigned)bf16_rne(v1) << 16) | bf16_rne(v0);
            o.y = ((unsigned)bf16_rne(v3) << 16) | bf16_rne(v2);
            o.z = ((unsigned)bf16_rne(v5) << 16) | bf16_rne(v4);
            o.w = ((unsigned)bf16_rne(v7) << 16) | bf16_rne(v6);
            *(uint4*)(m1s + e * 128 + ((g * 16) ^ ((e & 7) << 4))) = o;
        }
        __syncthreads();                          // B1: m1s + dstsL ready
        int nxt = tile + gridDim.x;
        if (nxt < ntiles) PRE(nxt);               // issue next tile's gathers
        // ---- stage 2: m1[128x64] @ W2[64x64] ----
        f32x4 acc2[2][2];
#pragma unroll
        for (int m = 0; m < 2; ++m)
#pragma unroll
            for (int n = 0; n < 2; ++n) {
                float b = b2s[32 * ni + 16 * n + l15];
                acc2[m][n] = (f32x4){b, b, b, b};
            }
        const int sw = (l15 & 7) << 4;
#pragma unroll
        for (int ks = 0; ks < 2; ++ks) {
            int kb = ks * 64 + l4 * 16;
            bf16x8 af[2], bfr[2];
#pragma unroll
            for (int m = 0; m < 2; ++m)
                af[m] = *(const bf16x8*)(m1s + (32 * mi + 16 * m + l15) * 128 + (kb ^ sw));
#pragma unroll
            for (int n = 0; n < 2; ++n)
                bfr[n] = *(const bf16x8*)(wt2s + (32 * ni + 16 * n + l15) * 128 + (kb ^ sw));
#pragma unroll
            for (int m = 0; m < 2; ++m)
#pragma unroll
                for (int n = 0; n < 2; ++n)
                    acc2[m][n] = mfma16(af[m], bfr[n], acc2[m][n]);
        }
        // m2 = silu -> f32 LDS (C/D: col=lane&15, row=(lane>>4)*4+reg)
#pragma unroll
        for (int m = 0; m < 2; ++m)
#pragma unroll
            for (int n = 0; n < 2; ++n)
#pragma unroll
                for (int r = 0; r < 4; ++r) {
                    int row = 32 * mi + 16 * m + l4 * 4 + r;
                    m2f[row * 68 + 32 * ni + 16 * n + l15] = silu_f(acc2[m][n][r]);
                }
        __syncthreads();                          // B2: m2f complete
        // ---- segmented reduce over sorted dsts, flush tails only ----
        const int tr = tid & 31, tc = tid >> 5;
        const int* dL = dstsL + buf * 128;
#pragma unroll
        for (int jj = 0; jj < 4; ++jj) {
            int r = 32 * jj + tr;
            int d = dL[r];
            float4 v = *(const float4*)&m2f[r * 68 + 4 * tc];
            unsigned f = (tr == 0 || dL[r - 1] != d) ? 1u : 0u;
#pragma unroll
            for (int s = 1; s < 32; s <<= 1) {
                float ux = __shfl_up(v.x, s, 32);
                float uy = __shfl_up(v.y, s, 32);
                float uz = __shfl_up(v.z, s, 32);
                float uw = __shfl_up(v.w, s, 32);
                unsigned uf = __shfl_up(f, s, 32);
                if (tr >= s) {
                    if (!f) { v.x += ux; v.y += uy; v.z += uz; v.w += uw; }
                    f |= uf;
                }
            }
            bool tail = (tr == 31) || (dL[r + 1] != d);
            if (tail) {
                float* bp = agg + 64 * d + 4 * tc;
                atomicAdd(bp + 0, v.x); atomicAdd(bp + 1, v.y);
                atomicAdd(bp + 2, v.z); atomicAdd(bp + 3, v.w);
            }
        }
        buf ^= 1;
    }
}

// ===========================================================================
// Row-MLP kernel (node update / readout) — unchanged (fp32, proven).
// ===========================================================================
template <int K1, bool SILU2, bool RESID, bool SCATTER>
__global__ __launch_bounds__(512, 1) void rowmlp_kernel(
    const float* __restrict__ A, const float* __restrict__ A2,
    const float* __restrict__ w1g, const float* __restrict__ b1g,
    const float* __restrict__ w2g, const float* __restrict__ b2g,
    const int* __restrict__ seg, float* __restrict__ outp,
    int nrows, int ntiles)
{
    constexpr int CST = K1 + 4;
    constexpr int QN  = K1 / 4;
    constexpr int QSH = (K1 == 128) ? 5 : 4;
    constexpr int REPS = QN / 4;

    extern __shared__ float lds[];
    float* ws1  = lds;
    float* ws2  = ws1 + K1 * 64;
    float* wb1  = ws2 + 4096;
    float* wb2  = wb1 + 64;
    float* cats = wb2 + 64;
    float* m1s  = cats + 128 * CST;
    int*   segs = (int*)(m1s + 128 * 68);

    const int tid = threadIdx.x;
    const int tr  = tid & 31;
    const int tc  = tid >> 5;

    for (int i = tid; i < K1 * 16; i += 512)
        *(float4*)&ws1[4 * i] = *(const float4*)&w1g[4 * i];
    for (int i = tid; i < 1024; i += 512)
        *(float4*)&ws2[4 * i] = *(const float4*)&w2g[4 * i];
    if (tid < 64) { wb1[tid] = b1g[tid]; wb2[tid] = b2g[tid]; }

    for (int tile = blockIdx.x; tile < ntiles; tile += gridDim.x) {
        const int base = tile * 128;
        __syncthreads();
        if (SCATTER) {
            if (tid < 128) segs[tid] = (base + tid < nrows) ? seg[base + tid] : -1;
        }
#pragma unroll
        for (int rep = 0; rep < REPS; ++rep) {
            int idx = rep * 512 + tid;
            int r = idx >> QSH, q = idx & (QN - 1);
            int n = base + r;
            float4 v = make_float4(0.f, 0.f, 0.f, 0.f);
            if (n < nrows) {
                if constexpr (K1 == 128)
                    v = (q < 16) ? *(const float4*)(A + 64 * n + 4 * q)
                                 : *(const float4*)(A2 + 64 * n + 4 * (q - 16));
                else
                    v = *(const float4*)(A + 64 * n + 4 * q);
            }
            *(float4*)&cats[r * CST + 4 * q] = v;
        }
        __syncthreads();
        float acc[4][4];
#pragma unroll
        for (int jj = 0; jj < 4; ++jj)
#pragma unroll
            for (int ii = 0; ii < 4; ++ii) acc[jj][ii] = wb1[4 * tc + ii];
#pragma unroll 4
        for (int k16 = 0; k16 < K1 / 4; ++k16) {
            float4 bv0 = *(const float4*)&ws1[(4 * k16 + 0) * 64 + 4 * tc];
            float4 bv1 = *(const float4*)&ws1[(4 * k16 + 1) * 64 + 4 * tc];
            float4 bv2 = *(const float4*)&ws1[(4 * k16 + 2) * 64 + 4 * tc];
            float4 bv3 = *(const float4*)&ws1[(4 * k16 + 3) * 64 + 4 * tc];
#pragma unroll
            for (int jj = 0; jj < 4; ++jj) {
                float4 av = *(const float4*)&cats[(tr + 32 * jj) * CST + 4 * k16];
                acc[jj][0] = fmaf(av.x, bv0.x, fmaf(av.y, bv1.x, fmaf(av.z, bv2.x, fmaf(av.w, bv3.x, acc[jj][0]))));
                acc[jj][1] = fmaf(av.x, bv0.y, fmaf(av.y, bv1.y, fmaf(av.z, bv2.y, fmaf(av.w, bv3.y, acc[jj][1]))));
                acc[jj][2] = fmaf(av.x, bv0.z, fmaf(av.y, bv1.z, fmaf(av.z, bv2.z, fmaf(av.w, bv3.z, acc[jj][2]))));
                acc[jj][3] = fmaf(av.x, bv0.w, fmaf(av.y, bv1.w, fmaf(av.z, bv2.w, fmaf(av.w, bv3.w, acc[jj][3]))));
            }
        }
#pragma unroll
        for (int jj = 0; jj < 4; ++jj) {
            float4 v;
            v.x = silu_f(acc[jj][0]); v.y = silu_f(acc[jj][1]);
            v.z = silu_f(acc[jj][2]); v.w = silu_f(acc[jj][3]);
            *(float4*)&m1s[(tr + 32 * jj) * 68 + 4 * tc] = v;
        }
        __syncthreads();
        float acc2[4][4];
#pragma unroll
        for (int jj = 0; jj < 4; ++jj)
#pragma unroll
            for (int ii = 0; ii < 4; ++ii) acc2[jj][ii] = wb2[4 * tc + ii];
#pragma unroll 4
        for (int k16 = 0; k16 < 16; ++k16) {
            float4 bv0 = *(const float4*)&ws2[(4 * k16 + 0) * 64 + 4 * tc];
            float4 bv1 = *(const float4*)&ws2[(4 * k16 + 1) * 64 + 4 * tc];
            float4 bv2 = *(const float4*)&ws2[(4 * k16 + 2) * 64 + 4 * tc];
            float4 bv3 = *(const float4*)&ws2[(4 * k16 + 3) * 64 + 4 * tc];
#pragma unroll
            for (int jj = 0; jj < 4; ++jj) {
                float4 av = *(const float4*)&m1s[(tr + 32 * jj) * 68 + 4 * k16];
                acc2[jj][0] = fmaf(av.x, bv0.x, fmaf(av.y, bv1.x, fmaf(av.z, bv2.x, fmaf(av.w, bv3.x, acc2[jj][0]))));
                acc2[jj][1] = fmaf(av.x, bv0.y, fmaf(av.y, bv1.y, fmaf(av.z, bv2.y, fmaf(av.w, bv3.y, acc2[jj][1]))));
                acc2[jj][2] = fmaf(av.x, bv0.z, fmaf(av.y, bv1.z, fmaf(av.z, bv2.z, fmaf(av.w, bv3.z, acc2[jj][2]))));
                acc2[jj][3] = fmaf(av.x, bv0.w, fmaf(av.y, bv1.w, fmaf(av.z, bv2.w, fmaf(av.w, bv3.w, acc2[jj][3]))));
            }
        }
#pragma unroll
        for (int jj = 0; jj < 4; ++jj) {
            int r = tr + 32 * jj;
            int n = base + r;
            float v[4];
#pragma unroll
            for (int ii = 0; ii < 4; ++ii)
                v[ii] = SILU2 ? silu_f(acc2[jj][ii]) : acc2[jj][ii];
            if (RESID) {
                float4 hold = *(const float4*)&cats[r * CST + 4 * tc];
                v[0] += hold.x; v[1] += hold.y; v[2] += hold.z; v[3] += hold.w;
            }
            if (SCATTER) {
                int gid = segs[r];
                float4 vv = (n < nrows) ? make_float4(v[0], v[1], v[2], v[3])
                                        : make_float4(0.f, 0.f, 0.f, 0.f);
                unsigned f = (tr == 0 || segs[r - 1] != gid) ? 1u : 0u;
#pragma unroll
                for (int s = 1; s < 32; s <<= 1) {
                    float ux = __shfl_up(vv.x, s, 32);
                    float uy = __shfl_up(vv.y, s, 32);
                    float uz = __shfl_up(vv.z, s, 32);
                    float uw = __shfl_up(vv.w, s, 32);
                    unsigned uf = __shfl_up(f, s, 32);
                    if (tr >= s) {
                        if (!f) { vv.x += ux; vv.y += uy; vv.z += uz; vv.w += uw; }
                        f |= uf;
                    }
                }
                bool tail = (tr == 31) || (segs[r + 1] != gid);
                if (tail && gid >= 0) {
                    float* bp = outp + 64 * gid + 4 * tc;
                    atomicAdd(bp + 0, vv.x); atomicAdd(bp + 1, vv.y);
                    atomicAdd(bp + 2, vv.z); atomicAdd(bp + 3, vv.w);
                }
            } else if (n < nrows) {
                *(float4*)&outp[64 * n + 4 * tc] = make_float4(v[0], v[1], v[2], v[3]);
            }
        }
    }
}

__global__ __launch_bounds__(256) void proj_kernel(
    const float* __restrict__ x, const float* __restrict__ w,
    const float* __restrict__ b, float* __restrict__ h, int n)
{
    int i = blockIdx.x * 256 + threadIdx.x;
    if (i >= n * 64) return;
    int node = i >> 6, j = i & 63;
    const float* xr = x + node * 14;
    float acc = b[j];
#pragma unroll
    for (int k = 0; k < 14; ++k) acc = fmaf(xr[k], w[k * 64 + j], acc);
    h[i] = acc;
}

__global__ __launch_bounds__(256) void head_kernel(
    const float* __restrict__ gsum,
    const float* __restrict__ w3, const float* __restrict__ b3,
    const float* __restrict__ w4, const float* __restrict__ b4,
    float* __restrict__ out, int g_count)
{
    int wid  = (blockIdx.x * 256 + threadIdx.x) >> 6;
    int lane = threadIdx.x & 63;
    if (wid >= g_count) return;
    float v = gsum[wid * 64 + lane];
    float t = b3[lane];
#pragma unroll
    for (int k = 0; k < 64; ++k) {
        float a = __shfl(v, k, 64);
        t = fmaf(a, w3[k * 64 + lane], t);
    }
    t = silu_f(t);
    float r = t * w4[lane];
#pragma unroll
    for (int off = 32; off; off >>= 1) r += __shfl_down(r, off, 64);
    if (lane == 0) out[wid] = r + b4[0];
}

extern "C" void kernel_launch(void* const* d_in, const int* in_sizes, int n_in,
                              void* d_out, int out_size, void* d_ws, size_t ws_size,
                              hipStream_t stream)
{
    const float* x      = (const float*)d_in[0];
    const int*   ei     = (const int*)d_in[2];
    const int*   batch  = (const int*)d_in[3];
    const float* proj_w = (const float*)d_in[4];
    const float* proj_b = (const float*)d_in[5];
    const float* ew1 = (const float*)d_in[6];
    const float* eb1 = (const float*)d_in[7];
    const float* ew2 = (const float*)d_in[8];
    const float* eb2 = (const float*)d_in[9];
    const float* nw1 = (const float*)d_in[10];
    const float* nb1 = (const float*)d_in[11];
    const float* nw2 = (const float*)d_in[12];
    const float* nb2 = (const float*)d_in[13];
    const float* l1w = (const float*)d_in[14]; const float* l1b = (const float*)d_in[15];
    const float* l2w = (const float*)d_in[16]; const float* l2b = (const float*)d_in[17];
    const float* l3w = (const float*)d_in[18]; const float* l3b = (const float*)d_in[19];
    const float* l4w = (const float*)d_in[20]; const float* l4b = (const float*)d_in[21];

    float* out  = (float*)d_out;
    float* h    = out + GG;                      // per_atom_out doubles as h

    float* agg  = (float*)d_ws;                  // [N,64]
    float* gsum = agg + (size_t)NN * 64;         // [G,64]
    float* Pt   = gsum + (size_t)GG * 64;        // [N,64] f32
    unsigned short* Pbu = (unsigned short*)(Pt + (size_t)NN * 64);  // [N,64] bf16 (f32-sized slot)
    int* deg    = (int*)((float*)Pbu + (size_t)NN * 64);
    int* rowptr = deg + NN;
    int* cursor = rowptr + NN + 1;
    int* srcsS  = cursor + NN;                   // [E]
    int* dstsS  = srcsS + EE;                    // [E]

    const size_t edge_lds = 8192 + 16384 + 34816 + 256 + 256 + 1024;  // 60928
    const size_t pk_lds   = (size_t)(8192 + 8704) * 4;                // 67584
    const size_t node_lds = (size_t)(8192 + 4096 + 128 + 128 * 132 + 128 * 68) * 4 + 128 * 4;
    const size_t ro_lds   = (size_t)(4096 + 4096 + 128 + 128 * 68 + 128 * 68) * 4 + 128 * 4;

    (void)hipFuncSetAttribute((const void*)edge_kernel,
                              hipFuncAttributeMaxDynamicSharedMemorySize, (int)edge_lds);
    (void)hipFuncSetAttribute((const void*)pk_kernel,
                              hipFuncAttributeMaxDynamicSharedMemorySize, (int)pk_lds);
    (void)hipFuncSetAttribute((const void*)(rowmlp_kernel<128, false, true, false>),
                              hipFuncAttributeMaxDynamicSharedMemorySize, (int)node_lds);
    (void)hipFuncSetAttribute((const void*)(rowmlp_kernel<64, false, false, true>),
                              hipFuncAttributeMaxDynamicSharedMemorySize, (int)ro_lds);

    // --- CSR build (dst-sorted edge arrays) ---
    hipMemsetAsync(deg, 0, (size_t)NN * sizeof(int), stream);
    hipMemsetAsync(gsum, 0, (size_t)GG * 64 * sizeof(float), stream);
    hist_kernel<<<(EE + 255) / 256, 256, 0, stream>>>(ei, deg);
    scan_kernel<<<1, 1024, 0, stream>>>(deg, rowptr, cursor);
    scatter_kernel<<<(EE + 255) / 256, 256, 0, stream>>>(ei, cursor, srcsS, dstsS);

    proj_kernel<<<(NN * 64 + 255) / 256, 256, 0, stream>>>(x, proj_w, proj_b, h, NN);

    const int etiles = EE / 128;               // 6250
    const int ntiles = (NN + 127) / 128;       // 391
    for (int l = 0; l < LL; ++l) {
        pk_kernel<<<ntiles, 512, pk_lds, stream>>>(h, ew1 + l * 8192, Pt, Pbu, ntiles);
        hipMemsetAsync(agg, 0, (size_t)NN * 64 * sizeof(float), stream);
        edge_kernel<<<512, 512, edge_lds, stream>>>(
            Pt, Pbu, srcsS, dstsS, eb1 + l * 64, ew2 + l * 4096, eb2 + l * 64,
            agg, etiles);
        rowmlp_kernel<128, false, true, false><<<196, 512, node_lds, stream>>>(
            h, agg, nw1 + l * 8192, nb1 + l * 64, nw2 + l * 4096, nb2 + l * 64,
            nullptr, h, NN, ntiles);
    }
    rowmlp_kernel<64, false, false, true><<<196, 512, ro_lds, stream>>>(
        h, nullptr, l1w, l1b, l2w, l2b, batch, gsum, NN, ntiles);
    head_kernel<<<GG / 4, 256, 0, stream>>>(gsum, l3w, l3b, l4w, l4b, out, GG);
}